// Round 3
// baseline (7301.453 us; speedup 1.0000x reference)
//
#include <hip/hip_runtime.h>
#include <math.h>

#define Bsz 32
#define Hd  512
#define SEQ 128
#define G4H 2048
#define BH  16384   // Bsz*Hd

typedef __attribute__((ext_vector_type(8))) short bf16x8;
typedef __attribute__((ext_vector_type(4))) float f32x4;
typedef __attribute__((ext_vector_type(4))) unsigned short us4;

__device__ __forceinline__ void gload16(const void* g, void* l) {
  __builtin_amdgcn_global_load_lds(
      (const __attribute__((address_space(1))) unsigned int*)g,
      (__attribute__((address_space(3))) unsigned int*)l, 16, 0, 0);
}

// ---------------- weight pre-pack (coalesced via LDS) ----------------
__global__ __launch_bounds__(256) void pack_w_k(const float* __restrict__ W,
                                                float* __restrict__ out) {
  __shared__ float Wl[8][512];
  const int blk = blockIdx.x, tid = threadIdx.x;
  #pragma unroll
  for (int r = 0; r < 8; ++r) {
    int j = ((r >> 1) << 9) + (blk << 1) + (r & 1);
    Wl[r][tid] = W[j * Hd + tid];
    Wl[r][tid + 256] = W[j * Hd + tid + 256];
  }
  __syncthreads();
  #pragma unroll
  for (int q = 0; q < 16; ++q) {
    int i = tid * 16 + q;
    int kk = i >> 8, rest = i & 255, ks2 = rest >> 3, jj = rest & 7;
    out[((size_t)blk << 12) + i] = Wl[jj][(ks2 << 4) + kk];
  }
}

__global__ __launch_bounds__(256) void bias_sum_k(const float* __restrict__ a,
                                                  const float* __restrict__ b,
                                                  float* __restrict__ out) {
  int i = blockIdx.x * 256 + threadIdx.x;
  if (i < G4H) out[i] = a[i] + b[i];
}

__global__ __launch_bounds__(256) void embed_k(const int* __restrict__ idx,
                                               const float* __restrict__ emb,
                                               float* __restrict__ out) {
  int t = blockIdx.x * 256 + threadIdx.x;
  int m = t >> 6, e4 = (t & 63) << 2;
  *(float4*)&out[(size_t)m * 256 + e4] =
      *(const float4*)&emb[(size_t)idx[m] * 256 + e4];
}

// ---------------- fp32 -> bf16 hi/lo split ----------------
__global__ __launch_bounds__(256) void split_k(const float* __restrict__ X,
                                               unsigned short* __restrict__ hi,
                                               unsigned short* __restrict__ lo) {
  int i = (blockIdx.x * 256 + threadIdx.x) << 2;
  float4 x = *(const float4*)&X[i];
  const float* xp = (const float*)&x;
  us4 h, l;
  #pragma unroll
  for (int e = 0; e < 4; ++e) {
    float v = xp[e];
    unsigned int u = __float_as_uint(v);
    unsigned int hr = (u + 0x7fffu + ((u >> 16) & 1u)) & 0xffff0000u;
    h[e] = (unsigned short)(hr >> 16);
    float rem = v - __uint_as_float(hr);
    unsigned int u2 = __float_as_uint(rem);
    l[e] = (unsigned short)((u2 + 0x7fffu + ((u2 >> 16) & 1u)) >> 16);
  }
  *(us4*)&hi[i] = h;
  *(us4*)&lo[i] = l;
}

// ---------------- fp32 NT GEMM (input gates) ----------------
__global__ __launch_bounds__(256, 2)
void gemm_nt_k(const float* __restrict__ A, const float* __restrict__ Wt,
               const float* __restrict__ bias, float* __restrict__ C,
               int K, int ldc)
{
  __shared__ float As[32 * 68];
  __shared__ float Ws[32 * 68];
  const int tid = threadIdx.x;
  const int m0 = blockIdx.y << 6, n0 = blockIdx.x << 6;
  const int tn = tid & 15, tm = tid >> 4;
  const int lr = tid >> 2, lk = (tid & 3) << 3;
  float acc[4][4] = {};
  for (int kt = 0; kt < K; kt += 32) {
    #pragma unroll
    for (int i = 0; i < 2; ++i) {
      float4 a = *(const float4*)&A[(size_t)(m0 + lr) * K + kt + lk + (i << 2)];
      float4 w = *(const float4*)&Wt[(size_t)(n0 + lr) * K + kt + lk + (i << 2)];
      const float* ap = (const float*)&a;
      const float* wp = (const float*)&w;
      #pragma unroll
      for (int d = 0; d < 4; ++d) {
        As[(lk + (i << 2) + d) * 68 + lr] = ap[d];
        Ws[(lk + (i << 2) + d) * 68 + lr] = wp[d];
      }
    }
    __syncthreads();
    #pragma unroll 8
    for (int kk = 0; kk < 32; ++kk) {
      float4 av = *(const float4*)&As[kk * 68 + (tm << 2)];
      float4 wv = *(const float4*)&Ws[kk * 68 + (tn << 2)];
      const float* ap = (const float*)&av;
      const float* wp = (const float*)&wv;
      #pragma unroll
      for (int i = 0; i < 4; ++i)
        #pragma unroll
        for (int j = 0; j < 4; ++j)
          acc[i][j] += ap[i] * wp[j];
    }
    __syncthreads();
  }
  #pragma unroll
  for (int i = 0; i < 4; ++i) {
    float4 o;
    float* op = (float*)&o;
    #pragma unroll
    for (int j = 0; j < 4; ++j) op[j] = acc[i][j] + bias[n0 + (tn << 2) + j];
    *(float4*)&C[(size_t)(m0 + (tm << 2) + i) * ldc + n0 + (tn << 2)] = o;
  }
}

// ---------------- bf16 MFMA 3-term split projection ----------------
__global__ __launch_bounds__(256)
void gemm_bf16_split_k(const unsigned short* __restrict__ Ahi,
                       const unsigned short* __restrict__ Alo,
                       const unsigned short* __restrict__ Bhi,
                       const unsigned short* __restrict__ Blo,
                       const float* __restrict__ bias,
                       float* __restrict__ C)
{
  __shared__ unsigned short As[4096];   // [128][32]
  __shared__ unsigned short Bs[4096];   // [128][32]
  const int tid = threadIdx.x;
  const int m0 = blockIdx.x << 7, n0 = blockIdx.y << 7;
  const int lane = tid & 63, wave = tid >> 6;
  const int wr = wave >> 1, wc = wave & 1;
  const int srow = wave * 32 + (lane >> 2);
  const int sk = (lane & 3) << 3;
  const int ldse = wave * 1024 + lane * 8;
  const int fr = lane & 15, fk = (lane >> 4) << 3;

  f32x4 acc[4][4];
  #pragma unroll
  for (int a = 0; a < 4; ++a)
    #pragma unroll
    for (int b = 0; b < 4; ++b) acc[a][b] = (f32x4){0.f, 0.f, 0.f, 0.f};

  #pragma unroll 1
  for (int seg = 0; seg < 3; ++seg) {
    const unsigned short* Ab = (seg == 2) ? Alo : Ahi;
    const unsigned short* Bb = (seg == 1) ? Blo : Bhi;
    #pragma unroll 1
    for (int kt = 0; kt < 512; kt += 32) {
      gload16(Ab + (size_t)(m0 + srow) * 512 + kt + sk, &As[ldse]);
      gload16(Ab + (size_t)(m0 + srow + 16) * 512 + kt + sk, &As[ldse + 512]);
      gload16(Bb + (size_t)(n0 + srow) * 512 + kt + sk, &Bs[ldse]);
      gload16(Bb + (size_t)(n0 + srow + 16) * 512 + kt + sk, &Bs[ldse + 512]);
      __syncthreads();
      bf16x8 af[4], bf[4];
      #pragma unroll
      for (int mf = 0; mf < 4; ++mf)
        af[mf] = *(const bf16x8*)&As[(wr * 64 + mf * 16 + fr) * 32 + fk];
      #pragma unroll
      for (int nf = 0; nf < 4; ++nf)
        bf[nf] = *(const bf16x8*)&Bs[(wc * 64 + nf * 16 + fr) * 32 + fk];
      #pragma unroll
      for (int mf = 0; mf < 4; ++mf)
        #pragma unroll
        for (int nf = 0; nf < 4; ++nf)
          acc[mf][nf] = __builtin_amdgcn_mfma_f32_16x16x32_bf16(af[mf], bf[nf],
                                                                acc[mf][nf], 0, 0, 0);
      __syncthreads();
    }
  }

  const int rgrp = (lane >> 4) << 2;
  #pragma unroll
  for (int nf = 0; nf < 4; ++nf) {
    int n = n0 + wc * 64 + nf * 16 + fr;
    float bn = bias[n];
    #pragma unroll
    for (int mf = 0; mf < 4; ++mf) {
      #pragma unroll
      for (int r = 0; r < 4; ++r) {
        int m = m0 + wr * 64 + mf * 16 + rgrp + r;
        C[(size_t)m * 32000 + n] = acc[mf][nf][r] + bn;
      }
    }
  }
}

// ---------------- grid barrier (all 256 blocks co-resident) ----------------
__device__ __forceinline__ void gbar(int* bar, int target) {
  __syncthreads();                       // all block threads' writes issued
  if (threadIdx.x == 0) {
    __hip_atomic_fetch_add(bar, 1, __ATOMIC_RELEASE, __HIP_MEMORY_SCOPE_AGENT);
    while (__hip_atomic_load(bar, __ATOMIC_RELAXED, __HIP_MEMORY_SCOPE_AGENT) < target)
      __builtin_amdgcn_s_sleep(1);
    (void)__hip_atomic_load(bar, __ATOMIC_ACQUIRE, __HIP_MEMORY_SCOPE_AGENT);
  }
  __syncthreads();
}

// ---------------- persistent LSTM: all 129 super-steps, weights LDS-resident ----------------
// Block blk owns cells n0=2*blk (all 4 gates, both layers). 1 block/CU, 256 blocks.
__global__ __launch_bounds__(256, 1)
void lstm_seq_k(const float* __restrict__ w0p,  // packed Whh0  [256][4096]
                const float* __restrict__ w1ap, // packed Wih1
                const float* __restrict__ w1bp, // packed Whh1
                const float* __restrict__ x0pre,// [B*SEQ][2048] input gates (+biases)
                const float* __restrict__ bias1,// [2048] bih1+bhh1
                float* __restrict__ h0buf, float* __restrict__ h1buf,
                float* __restrict__ c0, float* __restrict__ c1,
                float* __restrict__ dec_out,    // [B][SEQ][Hd] or nullptr
                int* __restrict__ bar)
{
  __shared__ float w0s[4096], w1as[4096], w1bs[4096];
  __shared__ float rbuf[8192];
  __shared__ float gbuf[256];

  const int blk = blockIdx.x, tid = threadIdx.x;
  const int bg = tid & 7, ks = tid >> 3;
  const int n0 = blk << 1;

  // stage all three packed weight panels once
  for (int i = tid * 4; i < 4096; i += 1024) {
    *(float4*)&w0s[i]  = *(const float4*)&w0p[((size_t)blk << 12) + i];
    *(float4*)&w1as[i] = *(const float4*)&w1ap[((size_t)blk << 12) + i];
    *(float4*)&w1bs[i] = *(const float4*)&w1bp[((size_t)blk << 12) + i];
  }
  __syncthreads();

  #pragma unroll 1
  for (int u = 0; u <= SEQ; ++u) {
    const bool doL0 = (u < SEQ), doL1 = (u >= 1);
    const int pA = (u + 1) & 1;  // h0 READ parity; h1 WRITE parity
    const int pW = u & 1;        // h0 WRITE parity; h1 READ parity

    // ---- h preloads into registers ----
    float hA[4][16], hB[4][16];
    {
      const float* h0p = h0buf + pA * BH;
      #pragma unroll
      for (int bi = 0; bi < 4; ++bi) {
        int b = (bg << 2) + bi;
        #pragma unroll
        for (int q = 0; q < 4; ++q) {
          float4 t = *(const float4*)&h0p[b * Hd + (ks << 4) + (q << 2)];
          hA[bi][q * 4 + 0] = t.x; hA[bi][q * 4 + 1] = t.y;
          hA[bi][q * 4 + 2] = t.z; hA[bi][q * 4 + 3] = t.w;
        }
      }
    }
    if (doL1) {
      const float* h1p = h1buf + pW * BH;
      #pragma unroll
      for (int bi = 0; bi < 4; ++bi) {
        int b = (bg << 2) + bi;
        #pragma unroll
        for (int q = 0; q < 4; ++q) {
          float4 t = *(const float4*)&h1p[b * Hd + (ks << 4) + (q << 2)];
          hB[bi][q * 4 + 0] = t.x; hB[bi][q * 4 + 1] = t.y;
          hB[bi][q * 4 + 2] = t.z; hB[bi][q * 4 + 3] = t.w;
        }
      }
    }

    __attribute__((aligned(16))) float acc0[8][4];
    __attribute__((aligned(16))) float acc1[8][4];
    #pragma unroll
    for (int jj = 0; jj < 8; ++jj)
      #pragma unroll
      for (int bi = 0; bi < 4; ++bi) { acc0[jj][bi] = 0.f; acc1[jj][bi] = 0.f; }

    const int wbase = ks << 3;
    if (doL0) {
      #pragma unroll
      for (int kk = 0; kk < 16; ++kk) {
        float4 wlo = *(const float4*)&w0s[(kk << 8) + wbase];
        float4 whi = *(const float4*)&w0s[(kk << 8) + wbase + 4];
        const float* wl = (const float*)&wlo;
        const float* wh = (const float*)&whi;
        #pragma unroll
        for (int jj = 0; jj < 4; ++jj)
          #pragma unroll
          for (int bi = 0; bi < 4; ++bi) {
            acc0[jj][bi]     += wl[jj] * hA[bi][kk];
            acc0[4 + jj][bi] += wh[jj] * hA[bi][kk];
          }
      }
    }
    if (doL1) {
      #pragma unroll
      for (int kk = 0; kk < 16; ++kk) {   // Wih1 . h0(u-1)
        float4 wlo = *(const float4*)&w1as[(kk << 8) + wbase];
        float4 whi = *(const float4*)&w1as[(kk << 8) + wbase + 4];
        const float* wl = (const float*)&wlo;
        const float* wh = (const float*)&whi;
        #pragma unroll
        for (int jj = 0; jj < 4; ++jj)
          #pragma unroll
          for (int bi = 0; bi < 4; ++bi) {
            acc1[jj][bi]     += wl[jj] * hA[bi][kk];
            acc1[4 + jj][bi] += wh[jj] * hA[bi][kk];
          }
      }
      #pragma unroll
      for (int kk = 0; kk < 16; ++kk) {   // Whh1 . h1(u-2)
        float4 wlo = *(const float4*)&w1bs[(kk << 8) + wbase];
        float4 whi = *(const float4*)&w1bs[(kk << 8) + wbase + 4];
        const float* wl = (const float*)&wlo;
        const float* wh = (const float*)&whi;
        #pragma unroll
        for (int jj = 0; jj < 4; ++jj)
          #pragma unroll
          for (int bi = 0; bi < 4; ++bi) {
            acc1[jj][bi]     += wl[jj] * hB[bi][kk];
            acc1[4 + jj][bi] += wh[jj] * hB[bi][kk];
          }
      }
    }

    // ---- layer0 reduce + pointwise ----
    if (doL0) {
      #pragma unroll
      for (int jj = 0; jj < 8; ++jj)
        *(float4*)&rbuf[(ks << 8) + (bg << 5) + ((jj ^ bg) << 2)] = *(const float4*)acc0[jj];
      __syncthreads();
      {
        int col = tid & 7, b = tid >> 3, bgr = b >> 2, bi = b & 3;
        float s = 0.f;
        #pragma unroll 8
        for (int k2 = 0; k2 < 32; ++k2)
          s += rbuf[(k2 << 8) + (bgr << 5) + ((col ^ bgr) << 2) + bi];
        int j = ((col >> 1) << 9) + n0 + (col & 1);
        s += x0pre[(size_t)(b * SEQ + u) * G4H + j];
        gbuf[(col << 5) + b] = s;
      }
      __syncthreads();
      if (tid < 64) {
        int cc = tid & 1, b2 = tid >> 1, n = n0 + cc;
        float gi = gbuf[((0 + cc) << 5) + b2];
        float gf = gbuf[((2 + cc) << 5) + b2];
        float gg = gbuf[((4 + cc) << 5) + b2];
        float go = gbuf[((6 + cc) << 5) + b2];
        float i_ = 1.f / (1.f + expf(-gi));
        float f_ = 1.f / (1.f + expf(-gf));
        float o_ = 1.f / (1.f + expf(-go));
        float g_ = tanhf(gg);
        float cold = c0[b2 * Hd + n];
        float cn = f_ * cold + i_ * g_;
        float hn = o_ * tanhf(cn);
        c0[b2 * Hd + n] = cn;
        h0buf[pW * BH + b2 * Hd + n] = hn;
      }
      __syncthreads();
    }

    // ---- layer1 reduce + pointwise ----
    if (doL1) {
      #pragma unroll
      for (int jj = 0; jj < 8; ++jj)
        *(float4*)&rbuf[(ks << 8) + (bg << 5) + ((jj ^ bg) << 2)] = *(const float4*)acc1[jj];
      __syncthreads();
      {
        int col = tid & 7, b = tid >> 3, bgr = b >> 2, bi = b & 3;
        float s = 0.f;
        #pragma unroll 8
        for (int k2 = 0; k2 < 32; ++k2)
          s += rbuf[(k2 << 8) + (bgr << 5) + ((col ^ bgr) << 2) + bi];
        int j = ((col >> 1) << 9) + n0 + (col & 1);
        s += bias1[j];
        gbuf[(col << 5) + b] = s;
      }
      __syncthreads();
      if (tid < 64) {
        int cc = tid & 1, b2 = tid >> 1, n = n0 + cc, t = u - 1;
        float gi = gbuf[((0 + cc) << 5) + b2];
        float gf = gbuf[((2 + cc) << 5) + b2];
        float gg = gbuf[((4 + cc) << 5) + b2];
        float go = gbuf[((6 + cc) << 5) + b2];
        float i_ = 1.f / (1.f + expf(-gi));
        float f_ = 1.f / (1.f + expf(-gf));
        float o_ = 1.f / (1.f + expf(-go));
        float g_ = tanhf(gg);
        float cold = c1[b2 * Hd + n];
        float cn = f_ * cold + i_ * g_;
        float hn = o_ * tanhf(cn);
        c1[b2 * Hd + n] = cn;
        h1buf[pA * BH + b2 * Hd + n] = hn;
        if (dec_out) dec_out[((size_t)b2 * SEQ + t) * Hd + n] = hn;
      }
    }

    if (u < SEQ) gbar(bar, 256 * (u + 1));
  }
}

// ---------------- host ----------------
extern "C" void kernel_launch(void* const* d_in, const int* in_sizes, int n_in,
                              void* d_out, int out_size, void* d_ws, size_t ws_size,
                              hipStream_t stream) {
  const int*   src  = (const int*)d_in[0];
  const int*   tgt  = (const int*)d_in[1];
  const float* emb  = (const float*)d_in[2];
  const float* Wout = (const float*)d_in[3];
  const float* bout = (const float*)d_in[4];
  const float* eWih0 = (const float*)d_in[5];
  const float* eWhh0 = (const float*)d_in[6];
  const float* ebih0 = (const float*)d_in[7];
  const float* ebhh0 = (const float*)d_in[8];
  const float* eWih1 = (const float*)d_in[9];
  const float* eWhh1 = (const float*)d_in[10];
  const float* ebih1 = (const float*)d_in[11];
  const float* ebhh1 = (const float*)d_in[12];
  const float* dWih0 = (const float*)d_in[13];
  const float* dWhh0 = (const float*)d_in[14];
  const float* dbih0 = (const float*)d_in[15];
  const float* dbhh0 = (const float*)d_in[16];
  const float* dWih1 = (const float*)d_in[17];
  const float* dWhh1 = (const float*)d_in[18];
  const float* dbih1 = (const float*)d_in[19];
  const float* dbhh1 = (const float*)d_in[20];

  float* ws = (float*)d_ws;
  char*  wsb = (char*)d_ws;
  const size_t OFF_EMB  = 0;         // 4096*256 f32
  const size_t OFF_X0   = 1048576;   // 4096*2048 f32 (reused enc then dec)
  const size_t OFF_W0E  = 9437184;
  const size_t OFF_W1AE = 10485760;
  const size_t OFF_W1BE = 11534336;
  const size_t OFF_W0D  = 12582912;
  const size_t OFF_W1AD = 13631488;
  const size_t OFF_W1BD = 14680064;
  const size_t OFF_BS0E = 15728640;
  const size_t OFF_B1E  = 15730688;
  const size_t OFF_BS0D = 15732736;
  const size_t OFF_B1D  = 15734784;
  const size_t OFF_H0   = 15736832;  // 2*BH
  const size_t OFF_H1   = 15769600;  // 2*BH
  const size_t OFF_C0   = 15802368;  // BH
  const size_t OFF_C1   = 15818752;  // BH
  const size_t OFF_BAR  = 15835136;  // 512 ints (enc bar at +0, dec bar at +256)
  const size_t OFF_DOUT = 15835648;  // 4096*512 f32 -> byte end 71,731,200
  // bf16 buffers (byte offsets)
  unsigned short* Bhi = (unsigned short*)(wsb + 71731200);   // 32000*512
  unsigned short* Blo = (unsigned short*)(wsb + 104499200);  // 32000*512
  unsigned short* Ahi = (unsigned short*)(wsb + 137267200);  // 4096*512
  unsigned short* Alo = (unsigned short*)(wsb + 141461504);  // 4096*512
  const bool use_mfma = ws_size >= 145655808ull;

  if (use_mfma)
    split_k<<<16000, 256, 0, stream>>>(Wout, Bhi, Blo);

  // pack weights + bias sums
  pack_w_k<<<256, 256, 0, stream>>>(eWhh0, ws + OFF_W0E);
  pack_w_k<<<256, 256, 0, stream>>>(eWih1, ws + OFF_W1AE);
  pack_w_k<<<256, 256, 0, stream>>>(eWhh1, ws + OFF_W1BE);
  pack_w_k<<<256, 256, 0, stream>>>(dWhh0, ws + OFF_W0D);
  pack_w_k<<<256, 256, 0, stream>>>(dWih1, ws + OFF_W1AD);
  pack_w_k<<<256, 256, 0, stream>>>(dWhh1, ws + OFF_W1BD);
  bias_sum_k<<<8, 256, 0, stream>>>(ebih0, ebhh0, ws + OFF_BS0E);
  bias_sum_k<<<8, 256, 0, stream>>>(ebih1, ebhh1, ws + OFF_B1E);
  bias_sum_k<<<8, 256, 0, stream>>>(dbih0, dbhh0, ws + OFF_BS0D);
  bias_sum_k<<<8, 256, 0, stream>>>(dbih1, dbhh1, ws + OFF_B1D);

  // zero LSTM state + barrier counters (every call -> graph replay safe)
  hipMemsetAsync(ws + OFF_H0, 0,
                 (size_t)(2 * BH + 2 * BH + BH + BH + 512) * 4, stream);

  // encoder
  embed_k<<<1024, 256, 0, stream>>>(src, emb, ws + OFF_EMB);
  gemm_nt_k<<<dim3(32, 64), 256, 0, stream>>>(ws + OFF_EMB, eWih0, ws + OFF_BS0E,
                                              ws + OFF_X0, 256, 2048);
  lstm_seq_k<<<256, 256, 0, stream>>>(ws + OFF_W0E, ws + OFF_W1AE, ws + OFF_W1BE,
                                      ws + OFF_X0, ws + OFF_B1E,
                                      ws + OFF_H0, ws + OFF_H1, ws + OFF_C0, ws + OFF_C1,
                                      nullptr, (int*)(ws + OFF_BAR));

  // decoder
  embed_k<<<1024, 256, 0, stream>>>(tgt, emb, ws + OFF_EMB);
  gemm_nt_k<<<dim3(32, 64), 256, 0, stream>>>(ws + OFF_EMB, dWih0, ws + OFF_BS0D,
                                              ws + OFF_X0, 256, 2048);
  lstm_seq_k<<<256, 256, 0, stream>>>(ws + OFF_W0D, ws + OFF_W1AD, ws + OFF_W1BD,
                                      ws + OFF_X0, ws + OFF_B1D,
                                      ws + OFF_H0, ws + OFF_H1, ws + OFF_C0, ws + OFF_C1,
                                      ws + OFF_DOUT, (int*)(ws + OFF_BAR) + 256);

  // vocab projection
  if (use_mfma) {
    split_k<<<2048, 256, 0, stream>>>(ws + OFF_DOUT, Ahi, Alo);
    gemm_bf16_split_k<<<dim3(32, 250), 256, 0, stream>>>(Ahi, Alo, Bhi, Blo,
                                                         bout, (float*)d_out);
  } else {
    gemm_nt_k<<<dim3(500, 64), 256, 0, stream>>>(ws + OFF_DOUT, Wout, bout,
                                                 (float*)d_out, 512, 32000);
  }
}

// Round 4
// 5700.552 us; speedup vs baseline: 1.2808x; 1.2808x over previous
//
#include <hip/hip_runtime.h>
#include <math.h>

#define Bsz 32
#define Hd  512
#define SEQ 128
#define G4H 2048
#define BH  16384   // Bsz*Hd

typedef __attribute__((ext_vector_type(8))) short bf16x8;
typedef __attribute__((ext_vector_type(4))) float f32x4;
typedef __attribute__((ext_vector_type(4))) unsigned short us4;

__device__ __forceinline__ void gload16(const void* g, void* l) {
  __builtin_amdgcn_global_load_lds(
      (const __attribute__((address_space(1))) unsigned int*)g,
      (__attribute__((address_space(3))) unsigned int*)l, 16, 0, 0);
}

// ---------------- weight pre-pack (coalesced via LDS) ----------------
__global__ __launch_bounds__(256) void pack_w_k(const float* __restrict__ W,
                                                float* __restrict__ out) {
  __shared__ float Wl[8][512];
  const int blk = blockIdx.x, tid = threadIdx.x;
  #pragma unroll
  for (int r = 0; r < 8; ++r) {
    int j = ((r >> 1) << 9) + (blk << 1) + (r & 1);
    Wl[r][tid] = W[j * Hd + tid];
    Wl[r][tid + 256] = W[j * Hd + tid + 256];
  }
  __syncthreads();
  #pragma unroll
  for (int q = 0; q < 16; ++q) {
    int i = tid * 16 + q;
    int kk = i >> 8, rest = i & 255, ks2 = rest >> 3, jj = rest & 7;
    out[((size_t)blk << 12) + i] = Wl[jj][(ks2 << 4) + kk];
  }
}

__global__ __launch_bounds__(256) void bias_sum_k(const float* __restrict__ a,
                                                  const float* __restrict__ b,
                                                  float* __restrict__ out) {
  int i = blockIdx.x * 256 + threadIdx.x;
  if (i < G4H) out[i] = a[i] + b[i];
}

__global__ __launch_bounds__(256) void embed_k(const int* __restrict__ idx,
                                               const float* __restrict__ emb,
                                               float* __restrict__ out) {
  int t = blockIdx.x * 256 + threadIdx.x;
  int m = t >> 6, e4 = (t & 63) << 2;
  *(float4*)&out[(size_t)m * 256 + e4] =
      *(const float4*)&emb[(size_t)idx[m] * 256 + e4];
}

// ---------------- fp32 -> bf16 hi/lo split ----------------
__global__ __launch_bounds__(256) void split_k(const float* __restrict__ X,
                                               unsigned short* __restrict__ hi,
                                               unsigned short* __restrict__ lo) {
  int i = (blockIdx.x * 256 + threadIdx.x) << 2;
  float4 x = *(const float4*)&X[i];
  const float* xp = (const float*)&x;
  us4 h, l;
  #pragma unroll
  for (int e = 0; e < 4; ++e) {
    float v = xp[e];
    unsigned int u = __float_as_uint(v);
    unsigned int hr = (u + 0x7fffu + ((u >> 16) & 1u)) & 0xffff0000u;
    h[e] = (unsigned short)(hr >> 16);
    float rem = v - __uint_as_float(hr);
    unsigned int u2 = __float_as_uint(rem);
    l[e] = (unsigned short)((u2 + 0x7fffu + ((u2 >> 16) & 1u)) >> 16);
  }
  *(us4*)&hi[i] = h;
  *(us4*)&lo[i] = l;
}

// ---------------- fp32 NT GEMM (input gates) ----------------
__global__ __launch_bounds__(256, 2)
void gemm_nt_k(const float* __restrict__ A, const float* __restrict__ Wt,
               const float* __restrict__ bias, float* __restrict__ C,
               int K, int ldc)
{
  __shared__ float As[32 * 68];
  __shared__ float Ws[32 * 68];
  const int tid = threadIdx.x;
  const int m0 = blockIdx.y << 6, n0 = blockIdx.x << 6;
  const int tn = tid & 15, tm = tid >> 4;
  const int lr = tid >> 2, lk = (tid & 3) << 3;
  float acc[4][4] = {};
  for (int kt = 0; kt < K; kt += 32) {
    #pragma unroll
    for (int i = 0; i < 2; ++i) {
      float4 a = *(const float4*)&A[(size_t)(m0 + lr) * K + kt + lk + (i << 2)];
      float4 w = *(const float4*)&Wt[(size_t)(n0 + lr) * K + kt + lk + (i << 2)];
      const float* ap = (const float*)&a;
      const float* wp = (const float*)&w;
      #pragma unroll
      for (int d = 0; d < 4; ++d) {
        As[(lk + (i << 2) + d) * 68 + lr] = ap[d];
        Ws[(lk + (i << 2) + d) * 68 + lr] = wp[d];
      }
    }
    __syncthreads();
    #pragma unroll 8
    for (int kk = 0; kk < 32; ++kk) {
      float4 av = *(const float4*)&As[kk * 68 + (tm << 2)];
      float4 wv = *(const float4*)&Ws[kk * 68 + (tn << 2)];
      const float* ap = (const float*)&av;
      const float* wp = (const float*)&wv;
      #pragma unroll
      for (int i = 0; i < 4; ++i)
        #pragma unroll
        for (int j = 0; j < 4; ++j)
          acc[i][j] += ap[i] * wp[j];
    }
    __syncthreads();
  }
  #pragma unroll
  for (int i = 0; i < 4; ++i) {
    float4 o;
    float* op = (float*)&o;
    #pragma unroll
    for (int j = 0; j < 4; ++j) op[j] = acc[i][j] + bias[n0 + (tn << 2) + j];
    *(float4*)&C[(size_t)(m0 + (tm << 2) + i) * ldc + n0 + (tn << 2)] = o;
  }
}

// ---------------- bf16 MFMA 3-term split projection ----------------
__global__ __launch_bounds__(256)
void gemm_bf16_split_k(const unsigned short* __restrict__ Ahi,
                       const unsigned short* __restrict__ Alo,
                       const unsigned short* __restrict__ Bhi,
                       const unsigned short* __restrict__ Blo,
                       const float* __restrict__ bias,
                       float* __restrict__ C)
{
  __shared__ unsigned short As[4096];   // [128][32]
  __shared__ unsigned short Bs[4096];   // [128][32]
  const int tid = threadIdx.x;
  const int m0 = blockIdx.x << 7, n0 = blockIdx.y << 7;
  const int lane = tid & 63, wave = tid >> 6;
  const int wr = wave >> 1, wc = wave & 1;
  const int srow = wave * 32 + (lane >> 2);
  const int sk = (lane & 3) << 3;
  const int ldse = wave * 1024 + lane * 8;
  const int fr = lane & 15, fk = (lane >> 4) << 3;

  f32x4 acc[4][4];
  #pragma unroll
  for (int a = 0; a < 4; ++a)
    #pragma unroll
    for (int b = 0; b < 4; ++b) acc[a][b] = (f32x4){0.f, 0.f, 0.f, 0.f};

  #pragma unroll 1
  for (int seg = 0; seg < 3; ++seg) {
    const unsigned short* Ab = (seg == 2) ? Alo : Ahi;
    const unsigned short* Bb = (seg == 1) ? Blo : Bhi;
    #pragma unroll 1
    for (int kt = 0; kt < 512; kt += 32) {
      gload16(Ab + (size_t)(m0 + srow) * 512 + kt + sk, &As[ldse]);
      gload16(Ab + (size_t)(m0 + srow + 16) * 512 + kt + sk, &As[ldse + 512]);
      gload16(Bb + (size_t)(n0 + srow) * 512 + kt + sk, &Bs[ldse]);
      gload16(Bb + (size_t)(n0 + srow + 16) * 512 + kt + sk, &Bs[ldse + 512]);
      __syncthreads();
      bf16x8 af[4], bf[4];
      #pragma unroll
      for (int mf = 0; mf < 4; ++mf)
        af[mf] = *(const bf16x8*)&As[(wr * 64 + mf * 16 + fr) * 32 + fk];
      #pragma unroll
      for (int nf = 0; nf < 4; ++nf)
        bf[nf] = *(const bf16x8*)&Bs[(wc * 64 + nf * 16 + fr) * 32 + fk];
      #pragma unroll
      for (int mf = 0; mf < 4; ++mf)
        #pragma unroll
        for (int nf = 0; nf < 4; ++nf)
          acc[mf][nf] = __builtin_amdgcn_mfma_f32_16x16x32_bf16(af[mf], bf[nf],
                                                                acc[mf][nf], 0, 0, 0);
      __syncthreads();
    }
  }

  const int rgrp = (lane >> 4) << 2;
  #pragma unroll
  for (int nf = 0; nf < 4; ++nf) {
    int n = n0 + wc * 64 + nf * 16 + fr;
    float bn = bias[n];
    #pragma unroll
    for (int mf = 0; mf < 4; ++mf) {
      #pragma unroll
      for (int r = 0; r < 4; ++r) {
        int m = m0 + wr * 64 + mf * 16 + rgrp + r;
        C[(size_t)m * 32000 + n] = acc[mf][nf][r] + bn;
      }
    }
  }
}

// ---------------- distributed-flag grid barrier (256 co-resident blocks) ----------------
// Block b release-stores epoch to its OWN 128B-spaced flag; wave0's 64 lanes poll
// 4 distinct flags each (256 parallel reads, no same-line contention, no RMW);
// single acquire load does the cross-XCD invalidate.
#define BARSTRIDE 32
__device__ __forceinline__ void gbar(int* arr, int epoch) {
  __syncthreads();                       // all block threads' writes issued
  const int tid = threadIdx.x;
  if (tid == 0)
    __hip_atomic_store(&arr[blockIdx.x * BARSTRIDE], epoch,
                       __ATOMIC_RELEASE, __HIP_MEMORY_SCOPE_AGENT);
  if (tid < 64) {
    const int* p0 = &arr[tid * BARSTRIDE];
    const int* p1 = &arr[(tid + 64) * BARSTRIDE];
    const int* p2 = &arr[(tid + 128) * BARSTRIDE];
    const int* p3 = &arr[(tid + 192) * BARSTRIDE];
    for (;;) {
      int a = __hip_atomic_load(p0, __ATOMIC_RELAXED, __HIP_MEMORY_SCOPE_AGENT);
      int b = __hip_atomic_load(p1, __ATOMIC_RELAXED, __HIP_MEMORY_SCOPE_AGENT);
      int c = __hip_atomic_load(p2, __ATOMIC_RELAXED, __HIP_MEMORY_SCOPE_AGENT);
      int d = __hip_atomic_load(p3, __ATOMIC_RELAXED, __HIP_MEMORY_SCOPE_AGENT);
      int m = min(min(a, b), min(c, d));
      if (__all(m >= epoch)) break;
      __builtin_amdgcn_s_sleep(1);
    }
    if (tid == 0)
      (void)__hip_atomic_load(&arr[0], __ATOMIC_ACQUIRE, __HIP_MEMORY_SCOPE_AGENT);
  }
  __syncthreads();
}

// ---------------- persistent LSTM: all 129 super-steps, weights LDS-resident ----------------
__global__ __launch_bounds__(256, 1)
void lstm_seq_k(const float* __restrict__ w0p,  // packed Whh0  [256][4096]
                const float* __restrict__ w1ap, // packed Wih1
                const float* __restrict__ w1bp, // packed Whh1
                const float* __restrict__ x0pre,// [B*SEQ][2048] input gates (+biases)
                const float* __restrict__ bias1,// [2048] bih1+bhh1
                float* __restrict__ h0buf, float* __restrict__ h1buf,
                float* __restrict__ c0, float* __restrict__ c1,
                float* __restrict__ dec_out,    // [B][SEQ][Hd] or nullptr
                int* __restrict__ bar)
{
  __shared__ float w0s[4096], w1as[4096], w1bs[4096];
  __shared__ float rbuf[8192];
  __shared__ float gbuf[256];

  const int blk = blockIdx.x, tid = threadIdx.x;
  const int bg = tid & 7, ks = tid >> 3;
  const int n0 = blk << 1;

  // stage all three packed weight panels once
  for (int i = tid * 4; i < 4096; i += 1024) {
    *(float4*)&w0s[i]  = *(const float4*)&w0p[((size_t)blk << 12) + i];
    *(float4*)&w1as[i] = *(const float4*)&w1ap[((size_t)blk << 12) + i];
    *(float4*)&w1bs[i] = *(const float4*)&w1bp[((size_t)blk << 12) + i];
  }
  __syncthreads();

  #pragma unroll 1
  for (int u = 0; u <= SEQ; ++u) {
    const bool doL0 = (u < SEQ), doL1 = (u >= 1);
    const int pA = (u + 1) & 1;  // h0 READ parity; h1 WRITE parity
    const int pW = u & 1;        // h0 WRITE parity; h1 READ parity

    // ---- h preloads into registers ----
    float hA[4][16], hB[4][16];
    {
      const float* h0p = h0buf + pA * BH;
      #pragma unroll
      for (int bi = 0; bi < 4; ++bi) {
        int b = (bg << 2) + bi;
        #pragma unroll
        for (int q = 0; q < 4; ++q) {
          float4 t = *(const float4*)&h0p[b * Hd + (ks << 4) + (q << 2)];
          hA[bi][q * 4 + 0] = t.x; hA[bi][q * 4 + 1] = t.y;
          hA[bi][q * 4 + 2] = t.z; hA[bi][q * 4 + 3] = t.w;
        }
      }
    }
    if (doL1) {
      const float* h1p = h1buf + pW * BH;
      #pragma unroll
      for (int bi = 0; bi < 4; ++bi) {
        int b = (bg << 2) + bi;
        #pragma unroll
        for (int q = 0; q < 4; ++q) {
          float4 t = *(const float4*)&h1p[b * Hd + (ks << 4) + (q << 2)];
          hB[bi][q * 4 + 0] = t.x; hB[bi][q * 4 + 1] = t.y;
          hB[bi][q * 4 + 2] = t.z; hB[bi][q * 4 + 3] = t.w;
        }
      }
    }

    __attribute__((aligned(16))) float acc0[8][4];
    __attribute__((aligned(16))) float acc1[8][4];
    #pragma unroll
    for (int jj = 0; jj < 8; ++jj)
      #pragma unroll
      for (int bi = 0; bi < 4; ++bi) { acc0[jj][bi] = 0.f; acc1[jj][bi] = 0.f; }

    const int wbase = ks << 3;
    if (doL0) {
      #pragma unroll
      for (int kk = 0; kk < 16; ++kk) {
        float4 wlo = *(const float4*)&w0s[(kk << 8) + wbase];
        float4 whi = *(const float4*)&w0s[(kk << 8) + wbase + 4];
        const float* wl = (const float*)&wlo;
        const float* wh = (const float*)&whi;
        #pragma unroll
        for (int jj = 0; jj < 4; ++jj)
          #pragma unroll
          for (int bi = 0; bi < 4; ++bi) {
            acc0[jj][bi]     += wl[jj] * hA[bi][kk];
            acc0[4 + jj][bi] += wh[jj] * hA[bi][kk];
          }
      }
    }
    if (doL1) {
      #pragma unroll
      for (int kk = 0; kk < 16; ++kk) {   // Wih1 . h0(u-1)
        float4 wlo = *(const float4*)&w1as[(kk << 8) + wbase];
        float4 whi = *(const float4*)&w1as[(kk << 8) + wbase + 4];
        const float* wl = (const float*)&wlo;
        const float* wh = (const float*)&whi;
        #pragma unroll
        for (int jj = 0; jj < 4; ++jj)
          #pragma unroll
          for (int bi = 0; bi < 4; ++bi) {
            acc1[jj][bi]     += wl[jj] * hA[bi][kk];
            acc1[4 + jj][bi] += wh[jj] * hA[bi][kk];
          }
      }
      #pragma unroll
      for (int kk = 0; kk < 16; ++kk) {   // Whh1 . h1(u-2)
        float4 wlo = *(const float4*)&w1bs[(kk << 8) + wbase];
        float4 whi = *(const float4*)&w1bs[(kk << 8) + wbase + 4];
        const float* wl = (const float*)&wlo;
        const float* wh = (const float*)&whi;
        #pragma unroll
        for (int jj = 0; jj < 4; ++jj)
          #pragma unroll
          for (int bi = 0; bi < 4; ++bi) {
            acc1[jj][bi]     += wl[jj] * hB[bi][kk];
            acc1[4 + jj][bi] += wh[jj] * hB[bi][kk];
          }
      }
    }

    // ---- layer0 reduce + pointwise ----
    if (doL0) {
      #pragma unroll
      for (int jj = 0; jj < 8; ++jj)
        *(float4*)&rbuf[(ks << 8) + (bg << 5) + ((jj ^ bg) << 2)] = *(const float4*)acc0[jj];
      __syncthreads();
      {
        int col = tid & 7, b = tid >> 3, bgr = b >> 2, bi = b & 3;
        float s = 0.f;
        #pragma unroll 8
        for (int k2 = 0; k2 < 32; ++k2)
          s += rbuf[(k2 << 8) + (bgr << 5) + ((col ^ bgr) << 2) + bi];
        int j = ((col >> 1) << 9) + n0 + (col & 1);
        s += x0pre[(size_t)(b * SEQ + u) * G4H + j];
        gbuf[(col << 5) + b] = s;
      }
      __syncthreads();
      if (tid < 64) {
        int cc = tid & 1, b2 = tid >> 1, n = n0 + cc;
        float gi = gbuf[((0 + cc) << 5) + b2];
        float gf = gbuf[((2 + cc) << 5) + b2];
        float gg = gbuf[((4 + cc) << 5) + b2];
        float go = gbuf[((6 + cc) << 5) + b2];
        float i_ = 1.f / (1.f + expf(-gi));
        float f_ = 1.f / (1.f + expf(-gf));
        float o_ = 1.f / (1.f + expf(-go));
        float g_ = tanhf(gg);
        float cold = c0[b2 * Hd + n];
        float cn = f_ * cold + i_ * g_;
        float hn = o_ * tanhf(cn);
        c0[b2 * Hd + n] = cn;
        h0buf[pW * BH + b2 * Hd + n] = hn;
      }
      __syncthreads();
    }

    // ---- layer1 reduce + pointwise ----
    if (doL1) {
      #pragma unroll
      for (int jj = 0; jj < 8; ++jj)
        *(float4*)&rbuf[(ks << 8) + (bg << 5) + ((jj ^ bg) << 2)] = *(const float4*)acc1[jj];
      __syncthreads();
      {
        int col = tid & 7, b = tid >> 3, bgr = b >> 2, bi = b & 3;
        float s = 0.f;
        #pragma unroll 8
        for (int k2 = 0; k2 < 32; ++k2)
          s += rbuf[(k2 << 8) + (bgr << 5) + ((col ^ bgr) << 2) + bi];
        int j = ((col >> 1) << 9) + n0 + (col & 1);
        s += bias1[j];
        gbuf[(col << 5) + b] = s;
      }
      __syncthreads();
      if (tid < 64) {
        int cc = tid & 1, b2 = tid >> 1, n = n0 + cc, t = u - 1;
        float gi = gbuf[((0 + cc) << 5) + b2];
        float gf = gbuf[((2 + cc) << 5) + b2];
        float gg = gbuf[((4 + cc) << 5) + b2];
        float go = gbuf[((6 + cc) << 5) + b2];
        float i_ = 1.f / (1.f + expf(-gi));
        float f_ = 1.f / (1.f + expf(-gf));
        float o_ = 1.f / (1.f + expf(-go));
        float g_ = tanhf(gg);
        float cold = c1[b2 * Hd + n];
        float cn = f_ * cold + i_ * g_;
        float hn = o_ * tanhf(cn);
        c1[b2 * Hd + n] = cn;
        h1buf[pA * BH + b2 * Hd + n] = hn;
        if (dec_out) dec_out[((size_t)b2 * SEQ + t) * Hd + n] = hn;
      }
    }

    if (u < SEQ) gbar(bar, u + 1);
  }
}

// ---------------- host ----------------
extern "C" void kernel_launch(void* const* d_in, const int* in_sizes, int n_in,
                              void* d_out, int out_size, void* d_ws, size_t ws_size,
                              hipStream_t stream) {
  const int*   src  = (const int*)d_in[0];
  const int*   tgt  = (const int*)d_in[1];
  const float* emb  = (const float*)d_in[2];
  const float* Wout = (const float*)d_in[3];
  const float* bout = (const float*)d_in[4];
  const float* eWih0 = (const float*)d_in[5];
  const float* eWhh0 = (const float*)d_in[6];
  const float* ebih0 = (const float*)d_in[7];
  const float* ebhh0 = (const float*)d_in[8];
  const float* eWih1 = (const float*)d_in[9];
  const float* eWhh1 = (const float*)d_in[10];
  const float* ebih1 = (const float*)d_in[11];
  const float* ebhh1 = (const float*)d_in[12];
  const float* dWih0 = (const float*)d_in[13];
  const float* dWhh0 = (const float*)d_in[14];
  const float* dbih0 = (const float*)d_in[15];
  const float* dbhh0 = (const float*)d_in[16];
  const float* dWih1 = (const float*)d_in[17];
  const float* dWhh1 = (const float*)d_in[18];
  const float* dbih1 = (const float*)d_in[19];
  const float* dbhh1 = (const float*)d_in[20];

  float* ws = (float*)d_ws;
  char*  wsb = (char*)d_ws;
  const size_t OFF_EMB  = 0;         // 4096*256 f32
  const size_t OFF_X0   = 1048576;   // 4096*2048 f32 (reused enc then dec)
  const size_t OFF_W0E  = 9437184;
  const size_t OFF_W1AE = 10485760;
  const size_t OFF_W1BE = 11534336;
  const size_t OFF_W0D  = 12582912;
  const size_t OFF_W1AD = 13631488;
  const size_t OFF_W1BD = 14680064;
  const size_t OFF_BS0E = 15728640;
  const size_t OFF_B1E  = 15730688;
  const size_t OFF_BS0D = 15732736;
  const size_t OFF_B1D  = 15734784;
  const size_t OFF_H0   = 15736832;  // 2*BH
  const size_t OFF_H1   = 15769600;  // 2*BH
  const size_t OFF_C0   = 15802368;  // BH
  const size_t OFF_C1   = 15818752;  // BH
  const size_t OFF_BAR  = 15835136;  // 2 x 8192 ints (enc, dec flag arrays)
  const size_t OFF_DOUT = 15851520;  // 4096*512 f32 -> byte end 71,794,688
  // bf16 buffers (byte offsets)
  unsigned short* Bhi = (unsigned short*)(wsb + 71794688);   // 32000*512
  unsigned short* Blo = (unsigned short*)(wsb + 104562688);  // 32000*512
  unsigned short* Ahi = (unsigned short*)(wsb + 137330688);  // 4096*512
  unsigned short* Alo = (unsigned short*)(wsb + 141524992);  // 4096*512
  const bool use_mfma = ws_size >= 145719296ull;

  if (use_mfma)
    split_k<<<16000, 256, 0, stream>>>(Wout, Bhi, Blo);

  // pack weights + bias sums
  pack_w_k<<<256, 256, 0, stream>>>(eWhh0, ws + OFF_W0E);
  pack_w_k<<<256, 256, 0, stream>>>(eWih1, ws + OFF_W1AE);
  pack_w_k<<<256, 256, 0, stream>>>(eWhh1, ws + OFF_W1BE);
  pack_w_k<<<256, 256, 0, stream>>>(dWhh0, ws + OFF_W0D);
  pack_w_k<<<256, 256, 0, stream>>>(dWih1, ws + OFF_W1AD);
  pack_w_k<<<256, 256, 0, stream>>>(dWhh1, ws + OFF_W1BD);
  bias_sum_k<<<8, 256, 0, stream>>>(ebih0, ebhh0, ws + OFF_BS0E);
  bias_sum_k<<<8, 256, 0, stream>>>(ebih1, ebhh1, ws + OFF_B1E);
  bias_sum_k<<<8, 256, 0, stream>>>(dbih0, dbhh0, ws + OFF_BS0D);
  bias_sum_k<<<8, 256, 0, stream>>>(dbih1, dbhh1, ws + OFF_B1D);

  // zero LSTM state + barrier flag arrays (every call -> graph replay safe)
  hipMemsetAsync(ws + OFF_H0, 0,
                 (size_t)(2 * BH + 2 * BH + BH + BH + 16384) * 4, stream);

  // encoder
  embed_k<<<1024, 256, 0, stream>>>(src, emb, ws + OFF_EMB);
  gemm_nt_k<<<dim3(32, 64), 256, 0, stream>>>(ws + OFF_EMB, eWih0, ws + OFF_BS0E,
                                              ws + OFF_X0, 256, 2048);
  lstm_seq_k<<<256, 256, 0, stream>>>(ws + OFF_W0E, ws + OFF_W1AE, ws + OFF_W1BE,
                                      ws + OFF_X0, ws + OFF_B1E,
                                      ws + OFF_H0, ws + OFF_H1, ws + OFF_C0, ws + OFF_C1,
                                      nullptr, (int*)(ws + OFF_BAR));

  // decoder
  embed_k<<<1024, 256, 0, stream>>>(tgt, emb, ws + OFF_EMB);
  gemm_nt_k<<<dim3(32, 64), 256, 0, stream>>>(ws + OFF_EMB, dWih0, ws + OFF_BS0D,
                                              ws + OFF_X0, 256, 2048);
  lstm_seq_k<<<256, 256, 0, stream>>>(ws + OFF_W0D, ws + OFF_W1AD, ws + OFF_W1BD,
                                      ws + OFF_X0, ws + OFF_B1D,
                                      ws + OFF_H0, ws + OFF_H1, ws + OFF_C0, ws + OFF_C1,
                                      ws + OFF_DOUT, (int*)(ws + OFF_BAR) + 8192);

  // vocab projection
  if (use_mfma) {
    split_k<<<2048, 256, 0, stream>>>(ws + OFF_DOUT, Ahi, Alo);
    gemm_bf16_split_k<<<dim3(32, 250), 256, 0, stream>>>(Ahi, Alo, Bhi, Blo,
                                                         bout, (float*)d_out);
  } else {
    gemm_nt_k<<<dim3(500, 64), 256, 0, stream>>>(ws + OFF_DOUT, Wout, bout,
                                                 (float*)d_out, 512, 32000);
  }
}

// Round 5
// 3435.545 us; speedup vs baseline: 2.1253x; 1.6593x over previous
//
#include <hip/hip_runtime.h>
#include <math.h>

#define Bsz 32
#define Hd  512
#define SEQ 128
#define G4H 2048
#define BH  16384   // Bsz*Hd

typedef __attribute__((ext_vector_type(8))) short bf16x8;
typedef __attribute__((ext_vector_type(4))) float f32x4;
typedef __attribute__((ext_vector_type(4))) unsigned short us4;

__device__ __forceinline__ void gload16(const void* g, void* l) {
  __builtin_amdgcn_global_load_lds(
      (const __attribute__((address_space(1))) unsigned int*)g,
      (__attribute__((address_space(3))) unsigned int*)l, 16, 0, 0);
}

// ---------------- weight pre-pack (coalesced via LDS) ----------------
__global__ __launch_bounds__(256) void pack_w_k(const float* __restrict__ W,
                                                float* __restrict__ out) {
  __shared__ float Wl[8][512];
  const int blk = blockIdx.x, tid = threadIdx.x;
  #pragma unroll
  for (int r = 0; r < 8; ++r) {
    int j = ((r >> 1) << 9) + (blk << 1) + (r & 1);
    Wl[r][tid] = W[j * Hd + tid];
    Wl[r][tid + 256] = W[j * Hd + tid + 256];
  }
  __syncthreads();
  #pragma unroll
  for (int q = 0; q < 16; ++q) {
    int i = tid * 16 + q;
    int kk = i >> 8, rest = i & 255, ks2 = rest >> 3, jj = rest & 7;
    out[((size_t)blk << 12) + i] = Wl[jj][(ks2 << 4) + kk];
  }
}

__global__ __launch_bounds__(256) void bias_sum_k(const float* __restrict__ a,
                                                  const float* __restrict__ b,
                                                  float* __restrict__ out) {
  int i = blockIdx.x * 256 + threadIdx.x;
  if (i < G4H) out[i] = a[i] + b[i];
}

__global__ __launch_bounds__(256) void embed_k(const int* __restrict__ idx,
                                               const float* __restrict__ emb,
                                               float* __restrict__ out) {
  int t = blockIdx.x * 256 + threadIdx.x;
  int m = t >> 6, e4 = (t & 63) << 2;
  *(float4*)&out[(size_t)m * 256 + e4] =
      *(const float4*)&emb[(size_t)idx[m] * 256 + e4];
}

// ---------------- fp32 -> bf16 hi/lo split ----------------
__global__ __launch_bounds__(256) void split_k(const float* __restrict__ X,
                                               unsigned short* __restrict__ hi,
                                               unsigned short* __restrict__ lo) {
  int i = (blockIdx.x * 256 + threadIdx.x) << 2;
  float4 x = *(const float4*)&X[i];
  const float* xp = (const float*)&x;
  us4 h, l;
  #pragma unroll
  for (int e = 0; e < 4; ++e) {
    float v = xp[e];
    unsigned int u = __float_as_uint(v);
    unsigned int hr = (u + 0x7fffu + ((u >> 16) & 1u)) & 0xffff0000u;
    h[e] = (unsigned short)(hr >> 16);
    float rem = v - __uint_as_float(hr);
    unsigned int u2 = __float_as_uint(rem);
    l[e] = (unsigned short)((u2 + 0x7fffu + ((u2 >> 16) & 1u)) >> 16);
  }
  *(us4*)&hi[i] = h;
  *(us4*)&lo[i] = l;
}

// ---------------- fp32 NT GEMM (input gates + fallback) ----------------
__global__ __launch_bounds__(256, 2)
void gemm_nt_k(const float* __restrict__ A, const float* __restrict__ Wt,
               const float* __restrict__ bias, float* __restrict__ C,
               int K, int ldc)
{
  __shared__ float As[32 * 68];
  __shared__ float Ws[32 * 68];
  const int tid = threadIdx.x;
  const int m0 = blockIdx.y << 6, n0 = blockIdx.x << 6;
  const int tn = tid & 15, tm = tid >> 4;
  const int lr = tid >> 2, lk = (tid & 3) << 3;
  float acc[4][4] = {};
  for (int kt = 0; kt < K; kt += 32) {
    #pragma unroll
    for (int i = 0; i < 2; ++i) {
      float4 a = *(const float4*)&A[(size_t)(m0 + lr) * K + kt + lk + (i << 2)];
      float4 w = *(const float4*)&Wt[(size_t)(n0 + lr) * K + kt + lk + (i << 2)];
      const float* ap = (const float*)&a;
      const float* wp = (const float*)&w;
      #pragma unroll
      for (int d = 0; d < 4; ++d) {
        As[(lk + (i << 2) + d) * 68 + lr] = ap[d];
        Ws[(lk + (i << 2) + d) * 68 + lr] = wp[d];
      }
    }
    __syncthreads();
    #pragma unroll 8
    for (int kk = 0; kk < 32; ++kk) {
      float4 av = *(const float4*)&As[kk * 68 + (tm << 2)];
      float4 wv = *(const float4*)&Ws[kk * 68 + (tn << 2)];
      const float* ap = (const float*)&av;
      const float* wp = (const float*)&wv;
      #pragma unroll
      for (int i = 0; i < 4; ++i)
        #pragma unroll
        for (int j = 0; j < 4; ++j)
          acc[i][j] += ap[i] * wp[j];
    }
    __syncthreads();
  }
  #pragma unroll
  for (int i = 0; i < 4; ++i) {
    float4 o;
    float* op = (float*)&o;
    #pragma unroll
    for (int j = 0; j < 4; ++j) op[j] = acc[i][j] + bias[n0 + (tn << 2) + j];
    *(float4*)&C[(size_t)(m0 + (tm << 2) + i) * ldc + n0 + (tn << 2)] = o;
  }
}

// ---------------- bf16 MFMA 3-term split projection ----------------
__global__ __launch_bounds__(256)
void gemm_bf16_split_k(const unsigned short* __restrict__ Ahi,
                       const unsigned short* __restrict__ Alo,
                       const unsigned short* __restrict__ Bhi,
                       const unsigned short* __restrict__ Blo,
                       const float* __restrict__ bias,
                       float* __restrict__ C)
{
  __shared__ unsigned short As[4096];   // [128][32]
  __shared__ unsigned short Bs[4096];   // [128][32]
  const int tid = threadIdx.x;
  const int m0 = blockIdx.x << 7, n0 = blockIdx.y << 7;
  const int lane = tid & 63, wave = tid >> 6;
  const int wr = wave >> 1, wc = wave & 1;
  const int srow = wave * 32 + (lane >> 2);
  const int sk = (lane & 3) << 3;
  const int ldse = wave * 1024 + lane * 8;
  const int fr = lane & 15, fk = (lane >> 4) << 3;

  f32x4 acc[4][4];
  #pragma unroll
  for (int a = 0; a < 4; ++a)
    #pragma unroll
    for (int b = 0; b < 4; ++b) acc[a][b] = (f32x4){0.f, 0.f, 0.f, 0.f};

  #pragma unroll 1
  for (int seg = 0; seg < 3; ++seg) {
    const unsigned short* Ab = (seg == 2) ? Alo : Ahi;
    const unsigned short* Bb = (seg == 1) ? Blo : Bhi;
    #pragma unroll 1
    for (int kt = 0; kt < 512; kt += 32) {
      gload16(Ab + (size_t)(m0 + srow) * 512 + kt + sk, &As[ldse]);
      gload16(Ab + (size_t)(m0 + srow + 16) * 512 + kt + sk, &As[ldse + 512]);
      gload16(Bb + (size_t)(n0 + srow) * 512 + kt + sk, &Bs[ldse]);
      gload16(Bb + (size_t)(n0 + srow + 16) * 512 + kt + sk, &Bs[ldse + 512]);
      __syncthreads();
      bf16x8 af[4], bf[4];
      #pragma unroll
      for (int mf = 0; mf < 4; ++mf)
        af[mf] = *(const bf16x8*)&As[(wr * 64 + mf * 16 + fr) * 32 + fk];
      #pragma unroll
      for (int nf = 0; nf < 4; ++nf)
        bf[nf] = *(const bf16x8*)&Bs[(wc * 64 + nf * 16 + fr) * 32 + fk];
      #pragma unroll
      for (int mf = 0; mf < 4; ++mf)
        #pragma unroll
        for (int nf = 0; nf < 4; ++nf)
          acc[mf][nf] = __builtin_amdgcn_mfma_f32_16x16x32_bf16(af[mf], bf[nf],
                                                                acc[mf][nf], 0, 0, 0);
      __syncthreads();
    }
  }

  const int rgrp = (lane >> 4) << 2;
  #pragma unroll
  for (int nf = 0; nf < 4; ++nf) {
    int n = n0 + wc * 64 + nf * 16 + fr;
    float bn = bias[n];
    #pragma unroll
    for (int mf = 0; mf < 4; ++mf) {
      #pragma unroll
      for (int r = 0; r < 4; ++r) {
        int m = m0 + wr * 64 + mf * 16 + rgrp + r;
        C[(size_t)m * 32000 + n] = acc[mf][nf][r] + bn;
      }
    }
  }
}

// ---------------- flag-only grid barrier (no wbl2 / no inv) ----------------
// Communicated data (h) is written via write-through sc1 atomic stores and read
// at never-before-cached addresses, so no cache maintenance is needed here.
// __syncthreads() drains each wave's vmcnt before s_barrier, so the sc1 data
// stores are L3-visible before any flag is set.
#define BARSTRIDE 32
__device__ __forceinline__ void gbar(int* arr, int epoch) {
  __syncthreads();
  const int tid = threadIdx.x;
  if (tid == 0) {
    asm volatile("s_waitcnt vmcnt(0)" ::: "memory");
    __hip_atomic_store(&arr[blockIdx.x * BARSTRIDE], epoch,
                       __ATOMIC_RELAXED, __HIP_MEMORY_SCOPE_AGENT);
  }
  if (tid < 64) {
    const int* p0 = &arr[tid * BARSTRIDE];
    const int* p1 = &arr[(tid + 64) * BARSTRIDE];
    const int* p2 = &arr[(tid + 128) * BARSTRIDE];
    const int* p3 = &arr[(tid + 192) * BARSTRIDE];
    for (;;) {
      int a = __hip_atomic_load(p0, __ATOMIC_RELAXED, __HIP_MEMORY_SCOPE_AGENT);
      int b = __hip_atomic_load(p1, __ATOMIC_RELAXED, __HIP_MEMORY_SCOPE_AGENT);
      int c = __hip_atomic_load(p2, __ATOMIC_RELAXED, __HIP_MEMORY_SCOPE_AGENT);
      int d = __hip_atomic_load(p3, __ATOMIC_RELAXED, __HIP_MEMORY_SCOPE_AGENT);
      int m = min(min(a, b), min(c, d));
      if (__all(m >= epoch)) break;
      __builtin_amdgcn_s_sleep(1);
    }
  }
  asm volatile("" ::: "memory");
  __syncthreads();
}

// ---------------- persistent LSTM: per-step h buffers, weights LDS-resident ----------------
// h0steps[u] = h0 state after step u (u in [0,128)); h1steps[t] = h1 state t.
// Initial states come from h0init/h1init (zeros for enc, enc finals for dec).
__global__ __launch_bounds__(256, 1)
void lstm_seq_k(const float* __restrict__ w0p,  // packed Whh0  [256][4096]
                const float* __restrict__ w1ap, // packed Wih1
                const float* __restrict__ w1bp, // packed Whh1
                const float* __restrict__ x0pre,// [B*SEQ][2048] input gates (+biases)
                const float* __restrict__ bias1,// [2048] bih1+bhh1
                float* __restrict__ h0steps, float* __restrict__ h1steps,
                const float* __restrict__ h0init, const float* __restrict__ h1init,
                float* __restrict__ c0, float* __restrict__ c1,
                float* __restrict__ dec_out,    // [B][SEQ][Hd] or nullptr
                int* __restrict__ bar)
{
  __shared__ float w0s[4096], w1as[4096], w1bs[4096];
  __shared__ float rbuf[8192];
  __shared__ float gbuf[256];

  const int blk = blockIdx.x, tid = threadIdx.x;
  const int bg = tid & 7, ks = tid >> 3;
  const int n0 = blk << 1;

  // stage all three packed weight panels once
  for (int i = tid * 4; i < 4096; i += 1024) {
    *(float4*)&w0s[i]  = *(const float4*)&w0p[((size_t)blk << 12) + i];
    *(float4*)&w1as[i] = *(const float4*)&w1ap[((size_t)blk << 12) + i];
    *(float4*)&w1bs[i] = *(const float4*)&w1bp[((size_t)blk << 12) + i];
  }
  __syncthreads();

  #pragma unroll 1
  for (int u = 0; u <= SEQ; ++u) {
    const bool doL0 = (u < SEQ), doL1 = (u >= 1);

    // ---- h preloads into registers (fresh per-step addresses) ----
    float hA[4][16], hB[4][16];
    {
      const float* h0p = (u == 0) ? h0init : h0steps + (size_t)(u - 1) * BH;
      #pragma unroll
      for (int bi = 0; bi < 4; ++bi) {
        int b = (bg << 2) + bi;
        #pragma unroll
        for (int q = 0; q < 4; ++q) {
          float4 t = *(const float4*)&h0p[b * Hd + (ks << 4) + (q << 2)];
          hA[bi][q * 4 + 0] = t.x; hA[bi][q * 4 + 1] = t.y;
          hA[bi][q * 4 + 2] = t.z; hA[bi][q * 4 + 3] = t.w;
        }
      }
    }
    if (doL1) {
      const float* h1p = (u == 1) ? h1init : h1steps + (size_t)(u - 2) * BH;
      #pragma unroll
      for (int bi = 0; bi < 4; ++bi) {
        int b = (bg << 2) + bi;
        #pragma unroll
        for (int q = 0; q < 4; ++q) {
          float4 t = *(const float4*)&h1p[b * Hd + (ks << 4) + (q << 2)];
          hB[bi][q * 4 + 0] = t.x; hB[bi][q * 4 + 1] = t.y;
          hB[bi][q * 4 + 2] = t.z; hB[bi][q * 4 + 3] = t.w;
        }
      }
    }

    __attribute__((aligned(16))) float acc0[8][4];
    __attribute__((aligned(16))) float acc1[8][4];
    #pragma unroll
    for (int jj = 0; jj < 8; ++jj)
      #pragma unroll
      for (int bi = 0; bi < 4; ++bi) { acc0[jj][bi] = 0.f; acc1[jj][bi] = 0.f; }

    const int wbase = ks << 3;
    if (doL0) {
      #pragma unroll
      for (int kk = 0; kk < 16; ++kk) {
        float4 wlo = *(const float4*)&w0s[(kk << 8) + wbase];
        float4 whi = *(const float4*)&w0s[(kk << 8) + wbase + 4];
        const float* wl = (const float*)&wlo;
        const float* wh = (const float*)&whi;
        #pragma unroll
        for (int jj = 0; jj < 4; ++jj)
          #pragma unroll
          for (int bi = 0; bi < 4; ++bi) {
            acc0[jj][bi]     += wl[jj] * hA[bi][kk];
            acc0[4 + jj][bi] += wh[jj] * hA[bi][kk];
          }
      }
    }
    if (doL1) {
      #pragma unroll
      for (int kk = 0; kk < 16; ++kk) {   // Wih1 . h0(u-1)
        float4 wlo = *(const float4*)&w1as[(kk << 8) + wbase];
        float4 whi = *(const float4*)&w1as[(kk << 8) + wbase + 4];
        const float* wl = (const float*)&wlo;
        const float* wh = (const float*)&whi;
        #pragma unroll
        for (int jj = 0; jj < 4; ++jj)
          #pragma unroll
          for (int bi = 0; bi < 4; ++bi) {
            acc1[jj][bi]     += wl[jj] * hA[bi][kk];
            acc1[4 + jj][bi] += wh[jj] * hA[bi][kk];
          }
      }
      #pragma unroll
      for (int kk = 0; kk < 16; ++kk) {   // Whh1 . h1(u-2)
        float4 wlo = *(const float4*)&w1bs[(kk << 8) + wbase];
        float4 whi = *(const float4*)&w1bs[(kk << 8) + wbase + 4];
        const float* wl = (const float*)&wlo;
        const float* wh = (const float*)&whi;
        #pragma unroll
        for (int jj = 0; jj < 4; ++jj)
          #pragma unroll
          for (int bi = 0; bi < 4; ++bi) {
            acc1[jj][bi]     += wl[jj] * hB[bi][kk];
            acc1[4 + jj][bi] += wh[jj] * hB[bi][kk];
          }
      }
    }

    // ---- layer0 reduce + pointwise ----
    if (doL0) {
      #pragma unroll
      for (int jj = 0; jj < 8; ++jj)
        *(float4*)&rbuf[(ks << 8) + (bg << 5) + ((jj ^ bg) << 2)] = *(const float4*)acc0[jj];
      __syncthreads();
      {
        int col = tid & 7, b = tid >> 3, bgr = b >> 2, bi = b & 3;
        float s = 0.f;
        #pragma unroll 8
        for (int k2 = 0; k2 < 32; ++k2)
          s += rbuf[(k2 << 8) + (bgr << 5) + ((col ^ bgr) << 2) + bi];
        int j = ((col >> 1) << 9) + n0 + (col & 1);
        s += x0pre[(size_t)(b * SEQ + u) * G4H + j];
        gbuf[(col << 5) + b] = s;
      }
      __syncthreads();
      if (tid < 64) {
        int cc = tid & 1, b2 = tid >> 1, n = n0 + cc;
        float gi = gbuf[((0 + cc) << 5) + b2];
        float gf = gbuf[((2 + cc) << 5) + b2];
        float gg = gbuf[((4 + cc) << 5) + b2];
        float go = gbuf[((6 + cc) << 5) + b2];
        float i_ = 1.f / (1.f + expf(-gi));
        float f_ = 1.f / (1.f + expf(-gf));
        float o_ = 1.f / (1.f + expf(-go));
        float g_ = tanhf(gg);
        float cold = c0[b2 * Hd + n];
        float cn = f_ * cold + i_ * g_;
        float hn = o_ * tanhf(cn);
        c0[b2 * Hd + n] = cn;
        __hip_atomic_store(&h0steps[(size_t)u * BH + b2 * Hd + n], hn,
                           __ATOMIC_RELAXED, __HIP_MEMORY_SCOPE_AGENT);
      }
      __syncthreads();
    }

    // ---- layer1 reduce + pointwise ----
    if (doL1) {
      #pragma unroll
      for (int jj = 0; jj < 8; ++jj)
        *(float4*)&rbuf[(ks << 8) + (bg << 5) + ((jj ^ bg) << 2)] = *(const float4*)acc1[jj];
      __syncthreads();
      {
        int col = tid & 7, b = tid >> 3, bgr = b >> 2, bi = b & 3;
        float s = 0.f;
        #pragma unroll 8
        for (int k2 = 0; k2 < 32; ++k2)
          s += rbuf[(k2 << 8) + (bgr << 5) + ((col ^ bgr) << 2) + bi];
        int j = ((col >> 1) << 9) + n0 + (col & 1);
        s += bias1[j];
        gbuf[(col << 5) + b] = s;
      }
      __syncthreads();
      if (tid < 64) {
        int cc = tid & 1, b2 = tid >> 1, n = n0 + cc, t = u - 1;
        float gi = gbuf[((0 + cc) << 5) + b2];
        float gf = gbuf[((2 + cc) << 5) + b2];
        float gg = gbuf[((4 + cc) << 5) + b2];
        float go = gbuf[((6 + cc) << 5) + b2];
        float i_ = 1.f / (1.f + expf(-gi));
        float f_ = 1.f / (1.f + expf(-gf));
        float o_ = 1.f / (1.f + expf(-go));
        float g_ = tanhf(gg);
        float cold = c1[b2 * Hd + n];
        float cn = f_ * cold + i_ * g_;
        float hn = o_ * tanhf(cn);
        c1[b2 * Hd + n] = cn;
        __hip_atomic_store(&h1steps[(size_t)t * BH + b2 * Hd + n], hn,
                           __ATOMIC_RELAXED, __HIP_MEMORY_SCOPE_AGENT);
        if (dec_out) dec_out[((size_t)b2 * SEQ + t) * Hd + n] = hn;
      }
    }

    if (u < SEQ) gbar(bar, u + 1);
  }
}

// ---------------- host ----------------
extern "C" void kernel_launch(void* const* d_in, const int* in_sizes, int n_in,
                              void* d_out, int out_size, void* d_ws, size_t ws_size,
                              hipStream_t stream) {
  const int*   src  = (const int*)d_in[0];
  const int*   tgt  = (const int*)d_in[1];
  const float* emb  = (const float*)d_in[2];
  const float* Wout = (const float*)d_in[3];
  const float* bout = (const float*)d_in[4];
  const float* eWih0 = (const float*)d_in[5];
  const float* eWhh0 = (const float*)d_in[6];
  const float* ebih0 = (const float*)d_in[7];
  const float* ebhh0 = (const float*)d_in[8];
  const float* eWih1 = (const float*)d_in[9];
  const float* eWhh1 = (const float*)d_in[10];
  const float* ebih1 = (const float*)d_in[11];
  const float* ebhh1 = (const float*)d_in[12];
  const float* dWih0 = (const float*)d_in[13];
  const float* dWhh0 = (const float*)d_in[14];
  const float* dbih0 = (const float*)d_in[15];
  const float* dbhh0 = (const float*)d_in[16];
  const float* dWih1 = (const float*)d_in[17];
  const float* dWhh1 = (const float*)d_in[18];
  const float* dbih1 = (const float*)d_in[19];
  const float* dbhh1 = (const float*)d_in[20];

  float* ws = (float*)d_ws;
  char*  wsb = (char*)d_ws;
  // float offsets
  const size_t OFF_EMB  = 0;          // 1,048,576 f (dead after input gemms)
  const size_t OFF_X0   = 1048576;    // 8,388,608 f
  const size_t OFF_W0E  = 9437184;
  const size_t OFF_W1AE = 10485760;
  const size_t OFF_W1BE = 11534336;
  const size_t OFF_W0D  = 12582912;
  const size_t OFF_W1AD = 13631488;
  const size_t OFF_W1BD = 14680064;
  const size_t OFF_BS0E = 15728640;
  const size_t OFF_B1E  = 15730688;
  const size_t OFF_BS0D = 15732736;
  const size_t OFF_B1D  = 15734784;
  const size_t OFF_H0   = 15736832;   // 128*BH = 2,097,152 f (per-step h0)
  const size_t OFF_H1   = 17833984;   // 128*BH
  const size_t OFF_C0   = 19931136;   // BH
  const size_t OFF_C1   = 19947520;   // BH
  const size_t OFF_Z    = 19963904;   // BH zeros (initial states)
  const size_t OFF_BAR  = 19980288;   // 2 x 8192 ints
  const size_t OFF_DOUT = 19996672;   // 2,097,152 f -> byte end 88,375,296
  // bf16 buffers (byte offsets). Ahi/Alo above DOUT; Bhi/Blo overlay the
  // low region (EMB/X0/weights/h0) which is dead by projection time.
  unsigned short* Ahi = (unsigned short*)(wsb + 88375296);   // 4096*512
  unsigned short* Alo = (unsigned short*)(wsb + 96763904);   // 4096*512
  unsigned short* Bhi = (unsigned short*)(wsb + 0);          // 32000*512
  unsigned short* Blo = (unsigned short*)(wsb + 32768000);   // 32000*512
  const bool use_mfma = ws_size >= 105152512ull;

  // pack weights + bias sums
  pack_w_k<<<256, 256, 0, stream>>>(eWhh0, ws + OFF_W0E);
  pack_w_k<<<256, 256, 0, stream>>>(eWih1, ws + OFF_W1AE);
  pack_w_k<<<256, 256, 0, stream>>>(eWhh1, ws + OFF_W1BE);
  pack_w_k<<<256, 256, 0, stream>>>(dWhh0, ws + OFF_W0D);
  pack_w_k<<<256, 256, 0, stream>>>(dWih1, ws + OFF_W1AD);
  pack_w_k<<<256, 256, 0, stream>>>(dWhh1, ws + OFF_W1BD);
  bias_sum_k<<<8, 256, 0, stream>>>(ebih0, ebhh0, ws + OFF_BS0E);
  bias_sum_k<<<8, 256, 0, stream>>>(ebih1, ebhh1, ws + OFF_B1E);
  bias_sum_k<<<8, 256, 0, stream>>>(dbih0, dbhh0, ws + OFF_BS0D);
  bias_sum_k<<<8, 256, 0, stream>>>(dbih1, dbhh1, ws + OFF_B1D);

  // zero c0/c1/zbuf/flags every call (graph replay safe)
  hipMemsetAsync(ws + OFF_C0, 0, (size_t)(4 * BH) * 4, stream);

  // encoder
  embed_k<<<1024, 256, 0, stream>>>(src, emb, ws + OFF_EMB);
  gemm_nt_k<<<dim3(32, 64), 256, 0, stream>>>(ws + OFF_EMB, eWih0, ws + OFF_BS0E,
                                              ws + OFF_X0, 256, 2048);
  lstm_seq_k<<<256, 256, 0, stream>>>(ws + OFF_W0E, ws + OFF_W1AE, ws + OFF_W1BE,
                                      ws + OFF_X0, ws + OFF_B1E,
                                      ws + OFF_H0, ws + OFF_H1,
                                      ws + OFF_Z, ws + OFF_Z,
                                      ws + OFF_C0, ws + OFF_C1,
                                      nullptr, (int*)(ws + OFF_BAR));

  // decoder (initial states = encoder finals, slot 127)
  embed_k<<<1024, 256, 0, stream>>>(tgt, emb, ws + OFF_EMB);
  gemm_nt_k<<<dim3(32, 64), 256, 0, stream>>>(ws + OFF_EMB, dWih0, ws + OFF_BS0D,
                                              ws + OFF_X0, 256, 2048);
  lstm_seq_k<<<256, 256, 0, stream>>>(ws + OFF_W0D, ws + OFF_W1AD, ws + OFF_W1BD,
                                      ws + OFF_X0, ws + OFF_B1D,
                                      ws + OFF_H0, ws + OFF_H1,
                                      ws + OFF_H0 + (size_t)127 * BH,
                                      ws + OFF_H1 + (size_t)127 * BH,
                                      ws + OFF_C0, ws + OFF_C1,
                                      ws + OFF_DOUT, (int*)(ws + OFF_BAR) + 8192);

  // vocab projection
  if (use_mfma) {
    split_k<<<2048, 256, 0, stream>>>(ws + OFF_DOUT, Ahi, Alo);
    split_k<<<16000, 256, 0, stream>>>(Wout, Bhi, Blo);   // overlays dead low region
    gemm_bf16_split_k<<<dim3(32, 250), 256, 0, stream>>>(Ahi, Alo, Bhi, Blo,
                                                         bout, (float*)d_out);
  } else {
    gemm_nt_k<<<dim3(500, 64), 256, 0, stream>>>(ws + OFF_DOUT, Wout, bout,
                                                 (float*)d_out, 512, 32000);
  }
}

// Round 6
// 3142.794 us; speedup vs baseline: 2.3232x; 1.0931x over previous
//
#include <hip/hip_runtime.h>
#include <math.h>

#define Bsz 32
#define Hd  512
#define SEQ 128
#define G4H 2048
#define BH  16384   // Bsz*Hd

typedef __attribute__((ext_vector_type(8))) short bf16x8;
typedef __attribute__((ext_vector_type(4))) float f32x4;
typedef __attribute__((ext_vector_type(4))) unsigned short us4;

__device__ __forceinline__ void gload16(const void* g, void* l) {
  __builtin_amdgcn_global_load_lds(
      (const __attribute__((address_space(1))) unsigned int*)g,
      (__attribute__((address_space(3))) unsigned int*)l, 16, 0, 0);
}

// ---------------- weight pre-pack (coalesced via LDS) ----------------
__global__ __launch_bounds__(256) void pack_w_k(const float* __restrict__ W,
                                                float* __restrict__ out) {
  __shared__ float Wl[8][512];
  const int blk = blockIdx.x, tid = threadIdx.x;
  #pragma unroll
  for (int r = 0; r < 8; ++r) {
    int j = ((r >> 1) << 9) + (blk << 1) + (r & 1);
    Wl[r][tid] = W[j * Hd + tid];
    Wl[r][tid + 256] = W[j * Hd + tid + 256];
  }
  __syncthreads();
  #pragma unroll
  for (int q = 0; q < 16; ++q) {
    int i = tid * 16 + q;
    int kk = i >> 8, rest = i & 255, ks2 = rest >> 3, jj = rest & 7;
    out[((size_t)blk << 12) + i] = Wl[jj][(ks2 << 4) + kk];
  }
}

__global__ __launch_bounds__(256) void bias_sum_k(const float* __restrict__ a,
                                                  const float* __restrict__ b,
                                                  float* __restrict__ out) {
  int i = blockIdx.x * 256 + threadIdx.x;
  if (i < G4H) out[i] = a[i] + b[i];
}

__global__ __launch_bounds__(256) void embed_k(const int* __restrict__ idx,
                                               const float* __restrict__ emb,
                                               float* __restrict__ out) {
  int t = blockIdx.x * 256 + threadIdx.x;
  int m = t >> 6, e4 = (t & 63) << 2;
  *(float4*)&out[(size_t)m * 256 + e4] =
      *(const float4*)&emb[(size_t)idx[m] * 256 + e4];
}

// ---------------- fp32 -> bf16 hi/lo split ----------------
__global__ __launch_bounds__(256) void split_k(const float* __restrict__ X,
                                               unsigned short* __restrict__ hi,
                                               unsigned short* __restrict__ lo) {
  int i = (blockIdx.x * 256 + threadIdx.x) << 2;
  float4 x = *(const float4*)&X[i];
  const float* xp = (const float*)&x;
  us4 h, l;
  #pragma unroll
  for (int e = 0; e < 4; ++e) {
    float v = xp[e];
    unsigned int u = __float_as_uint(v);
    unsigned int hr = (u + 0x7fffu + ((u >> 16) & 1u)) & 0xffff0000u;
    h[e] = (unsigned short)(hr >> 16);
    float rem = v - __uint_as_float(hr);
    unsigned int u2 = __float_as_uint(rem);
    l[e] = (unsigned short)((u2 + 0x7fffu + ((u2 >> 16) & 1u)) >> 16);
  }
  *(us4*)&hi[i] = h;
  *(us4*)&lo[i] = l;
}

// ---------------- fp32 NT GEMM (input gates + fallback) ----------------
__global__ __launch_bounds__(256, 2)
void gemm_nt_k(const float* __restrict__ A, const float* __restrict__ Wt,
               const float* __restrict__ bias, float* __restrict__ C,
               int K, int ldc)
{
  __shared__ float As[32 * 68];
  __shared__ float Ws[32 * 68];
  const int tid = threadIdx.x;
  const int m0 = blockIdx.y << 6, n0 = blockIdx.x << 6;
  const int tn = tid & 15, tm = tid >> 4;
  const int lr = tid >> 2, lk = (tid & 3) << 3;
  float acc[4][4] = {};
  for (int kt = 0; kt < K; kt += 32) {
    #pragma unroll
    for (int i = 0; i < 2; ++i) {
      float4 a = *(const float4*)&A[(size_t)(m0 + lr) * K + kt + lk + (i << 2)];
      float4 w = *(const float4*)&Wt[(size_t)(n0 + lr) * K + kt + lk + (i << 2)];
      const float* ap = (const float*)&a;
      const float* wp = (const float*)&w;
      #pragma unroll
      for (int d = 0; d < 4; ++d) {
        As[(lk + (i << 2) + d) * 68 + lr] = ap[d];
        Ws[(lk + (i << 2) + d) * 68 + lr] = wp[d];
      }
    }
    __syncthreads();
    #pragma unroll 8
    for (int kk = 0; kk < 32; ++kk) {
      float4 av = *(const float4*)&As[kk * 68 + (tm << 2)];
      float4 wv = *(const float4*)&Ws[kk * 68 + (tn << 2)];
      const float* ap = (const float*)&av;
      const float* wp = (const float*)&wv;
      #pragma unroll
      for (int i = 0; i < 4; ++i)
        #pragma unroll
        for (int j = 0; j < 4; ++j)
          acc[i][j] += ap[i] * wp[j];
    }
    __syncthreads();
  }
  #pragma unroll
  for (int i = 0; i < 4; ++i) {
    float4 o;
    float* op = (float*)&o;
    #pragma unroll
    for (int j = 0; j < 4; ++j) op[j] = acc[i][j] + bias[n0 + (tn << 2) + j];
    *(float4*)&C[(size_t)(m0 + (tm << 2) + i) * ldc + n0 + (tn << 2)] = o;
  }
}

// ---------------- bf16 MFMA 3-term split projection ----------------
__global__ __launch_bounds__(256)
void gemm_bf16_split_k(const unsigned short* __restrict__ Ahi,
                       const unsigned short* __restrict__ Alo,
                       const unsigned short* __restrict__ Bhi,
                       const unsigned short* __restrict__ Blo,
                       const float* __restrict__ bias,
                       float* __restrict__ C)
{
  __shared__ unsigned short As[4096];   // [128][32]
  __shared__ unsigned short Bs[4096];   // [128][32]
  const int tid = threadIdx.x;
  const int m0 = blockIdx.x << 7, n0 = blockIdx.y << 7;
  const int lane = tid & 63, wave = tid >> 6;
  const int wr = wave >> 1, wc = wave & 1;
  const int srow = wave * 32 + (lane >> 2);
  const int sk = (lane & 3) << 3;
  const int ldse = wave * 1024 + lane * 8;
  const int fr = lane & 15, fk = (lane >> 4) << 3;

  f32x4 acc[4][4];
  #pragma unroll
  for (int a = 0; a < 4; ++a)
    #pragma unroll
    for (int b = 0; b < 4; ++b) acc[a][b] = (f32x4){0.f, 0.f, 0.f, 0.f};

  #pragma unroll 1
  for (int seg = 0; seg < 3; ++seg) {
    const unsigned short* Ab = (seg == 2) ? Alo : Ahi;
    const unsigned short* Bb = (seg == 1) ? Blo : Bhi;
    #pragma unroll 1
    for (int kt = 0; kt < 512; kt += 32) {
      gload16(Ab + (size_t)(m0 + srow) * 512 + kt + sk, &As[ldse]);
      gload16(Ab + (size_t)(m0 + srow + 16) * 512 + kt + sk, &As[ldse + 512]);
      gload16(Bb + (size_t)(n0 + srow) * 512 + kt + sk, &Bs[ldse]);
      gload16(Bb + (size_t)(n0 + srow + 16) * 512 + kt + sk, &Bs[ldse + 512]);
      __syncthreads();
      bf16x8 af[4], bf[4];
      #pragma unroll
      for (int mf = 0; mf < 4; ++mf)
        af[mf] = *(const bf16x8*)&As[(wr * 64 + mf * 16 + fr) * 32 + fk];
      #pragma unroll
      for (int nf = 0; nf < 4; ++nf)
        bf[nf] = *(const bf16x8*)&Bs[(wc * 64 + nf * 16 + fr) * 32 + fk];
      #pragma unroll
      for (int mf = 0; mf < 4; ++mf)
        #pragma unroll
        for (int nf = 0; nf < 4; ++nf)
          acc[mf][nf] = __builtin_amdgcn_mfma_f32_16x16x32_bf16(af[mf], bf[nf],
                                                                acc[mf][nf], 0, 0, 0);
      __syncthreads();
    }
  }

  const int rgrp = (lane >> 4) << 2;
  #pragma unroll
  for (int nf = 0; nf < 4; ++nf) {
    int n = n0 + wc * 64 + nf * 16 + fr;
    float bn = bias[n];
    #pragma unroll
    for (int mf = 0; mf < 4; ++mf) {
      #pragma unroll
      for (int r = 0; r < 4; ++r) {
        int m = m0 + wr * 64 + mf * 16 + rgrp + r;
        C[(size_t)m * 32000 + n] = acc[mf][nf][r] + bn;
      }
    }
  }
}

// ---------------- split-phase flag sync (write-once slots, no cache maint) ----------------
#define BARSTRIDE 32
__device__ __forceinline__ void pollwait(const int* arr, int target) {
  const int tid = threadIdx.x;
  if (tid < 64) {
    const int* p0 = &arr[tid * BARSTRIDE];
    const int* p1 = &arr[(tid + 64) * BARSTRIDE];
    const int* p2 = &arr[(tid + 128) * BARSTRIDE];
    const int* p3 = &arr[(tid + 192) * BARSTRIDE];
    for (;;) {
      int a = __hip_atomic_load(p0, __ATOMIC_RELAXED, __HIP_MEMORY_SCOPE_AGENT);
      int b = __hip_atomic_load(p1, __ATOMIC_RELAXED, __HIP_MEMORY_SCOPE_AGENT);
      int c = __hip_atomic_load(p2, __ATOMIC_RELAXED, __HIP_MEMORY_SCOPE_AGENT);
      int d = __hip_atomic_load(p3, __ATOMIC_RELAXED, __HIP_MEMORY_SCOPE_AGENT);
      if (__all(min(min(a, b), min(c, d)) >= target)) break;
      __builtin_amdgcn_s_sleep(1);
    }
  }
  __syncthreads();
}
// wave0 issued the data stores; drain vmcnt then set this block's flag
__device__ __forceinline__ void publish(int* arr, int val) {
  if (threadIdx.x == 0) {
    asm volatile("s_waitcnt vmcnt(0)" ::: "memory");
    __hip_atomic_store(&arr[blockIdx.x * BARSTRIDE], val,
                       __ATOMIC_RELAXED, __HIP_MEMORY_SCOPE_AGENT);
  }
}

// ---------------- persistent LSTM: split-phase dataflow, per-step h slots ----------------
__global__ __launch_bounds__(256, 1)
void lstm_seq_k(const float* __restrict__ w0p,  // packed Whh0  [256][4096]
                const float* __restrict__ w1ap, // packed Wih1
                const float* __restrict__ w1bp, // packed Whh1
                const float* __restrict__ x0pre,// [B*SEQ][2048] input gates (+biases)
                const float* __restrict__ bias1,// [2048] bih1+bhh1
                float* __restrict__ h0steps, float* __restrict__ h1steps,
                const float* __restrict__ h0init, const float* __restrict__ h1init,
                const float* __restrict__ c0init, const float* __restrict__ c1init,
                float* __restrict__ c0fin, float* __restrict__ c1fin,
                float* __restrict__ dec_out,    // [B][SEQ][Hd] or nullptr
                int* __restrict__ flag0, int* __restrict__ flag1)
{
  __shared__ float w0s[4096], w1as[4096], w1bs[4096];
  __shared__ float rbuf[8192];
  __shared__ float gbuf[256];

  const int blk = blockIdx.x, tid = threadIdx.x;
  const int bg = tid & 7, ks = tid >> 3;
  const int n0 = blk << 1;

  // stage all three packed weight panels once
  for (int i = tid * 4; i < 4096; i += 1024) {
    *(float4*)&w0s[i]  = *(const float4*)&w0p[((size_t)blk << 12) + i];
    *(float4*)&w1as[i] = *(const float4*)&w1ap[((size_t)blk << 12) + i];
    *(float4*)&w1bs[i] = *(const float4*)&w1bp[((size_t)blk << 12) + i];
  }

  // loop-invariant per-thread state
  const int cc_ = tid & 1, b2_ = tid >> 1, nn_ = n0 + cc_;      // pointwise lanes
  float creg0 = 0.f, creg1 = 0.f;
  if (tid < 64) {
    creg0 = c0init[b2_ * Hd + nn_];
    creg1 = c1init[b2_ * Hd + nn_];
  }
  const int rcol = tid & 7, rb = tid >> 3, rbgr = rb >> 2, rbi = rb & 3;  // reduce lanes
  const int rj = ((rcol >> 1) << 9) + n0 + (rcol & 1);
  const float bv = bias1[rj];
  const float* xbase = x0pre + (size_t)rb * SEQ * G4H + rj;
  __syncthreads();

  #pragma unroll 1
  for (int u = 0; u <= SEQ; ++u) {
    const bool doL0 = (u < SEQ), doL1 = (u >= 1);

    if (u > 0) pollwait(flag0, u);   // h0(u-1) ready

    // ---- hA load + x0 prefetch ----
    float hA[4][16], hB[4][16];
    {
      const float* h0p = (u == 0) ? h0init : h0steps + (size_t)(u - 1) * BH;
      #pragma unroll
      for (int bi = 0; bi < 4; ++bi) {
        int b = (bg << 2) + bi;
        #pragma unroll
        for (int q = 0; q < 4; ++q) {
          float4 t = *(const float4*)&h0p[b * Hd + (ks << 4) + (q << 2)];
          hA[bi][q * 4 + 0] = t.x; hA[bi][q * 4 + 1] = t.y;
          hA[bi][q * 4 + 2] = t.z; hA[bi][q * 4 + 3] = t.w;
        }
      }
    }
    float xv = doL0 ? xbase[(size_t)u * G4H] : 0.f;

    __attribute__((aligned(16))) float acc0[8][4];
    __attribute__((aligned(16))) float acc1[8][4];
    #pragma unroll
    for (int jj = 0; jj < 8; ++jj)
      #pragma unroll
      for (int bi = 0; bi < 4; ++bi) { acc0[jj][bi] = 0.f; acc1[jj][bi] = 0.f; }

    const int wbase = ks << 3;
    // ---- hA-only matmuls: Whh0.hA and Wih1.hA ----
    if (doL0) {
      #pragma unroll
      for (int kk = 0; kk < 16; ++kk) {
        float4 wlo = *(const float4*)&w0s[(kk << 8) + wbase];
        float4 whi = *(const float4*)&w0s[(kk << 8) + wbase + 4];
        const float* wl = (const float*)&wlo;
        const float* wh = (const float*)&whi;
        #pragma unroll
        for (int jj = 0; jj < 4; ++jj)
          #pragma unroll
          for (int bi = 0; bi < 4; ++bi) {
            acc0[jj][bi]     += wl[jj] * hA[bi][kk];
            acc0[4 + jj][bi] += wh[jj] * hA[bi][kk];
          }
      }
    }
    if (doL1) {
      #pragma unroll
      for (int kk = 0; kk < 16; ++kk) {
        float4 wlo = *(const float4*)&w1as[(kk << 8) + wbase];
        float4 whi = *(const float4*)&w1as[(kk << 8) + wbase + 4];
        const float* wl = (const float*)&wlo;
        const float* wh = (const float*)&whi;
        #pragma unroll
        for (int jj = 0; jj < 4; ++jj)
          #pragma unroll
          for (int bi = 0; bi < 4; ++bi) {
            acc1[jj][bi]     += wl[jj] * hA[bi][kk];
            acc1[4 + jj][bi] += wh[jj] * hA[bi][kk];
          }
      }
    }

    if (u >= 2) pollwait(flag1, u - 1);  // h1(u-2) ready

    if (doL1) {
      const float* h1p = (u == 1) ? h1init : h1steps + (size_t)(u - 2) * BH;
      #pragma unroll
      for (int bi = 0; bi < 4; ++bi) {
        int b = (bg << 2) + bi;
        #pragma unroll
        for (int q = 0; q < 4; ++q) {
          float4 t = *(const float4*)&h1p[b * Hd + (ks << 4) + (q << 2)];
          hB[bi][q * 4 + 0] = t.x; hB[bi][q * 4 + 1] = t.y;
          hB[bi][q * 4 + 2] = t.z; hB[bi][q * 4 + 3] = t.w;
        }
      }
      #pragma unroll
      for (int kk = 0; kk < 16; ++kk) {   // Whh1 . hB
        float4 wlo = *(const float4*)&w1bs[(kk << 8) + wbase];
        float4 whi = *(const float4*)&w1bs[(kk << 8) + wbase + 4];
        const float* wl = (const float*)&wlo;
        const float* wh = (const float*)&whi;
        #pragma unroll
        for (int jj = 0; jj < 4; ++jj)
          #pragma unroll
          for (int bi = 0; bi < 4; ++bi) {
            acc1[jj][bi]     += wl[jj] * hB[bi][kk];
            acc1[4 + jj][bi] += wh[jj] * hB[bi][kk];
          }
      }
    }

    // ---- layer0 reduce + pointwise + early publish ----
    if (doL0) {
      #pragma unroll
      for (int jj = 0; jj < 8; ++jj)
        *(float4*)&rbuf[(ks << 8) + (bg << 5) + ((jj ^ bg) << 2)] = *(const float4*)acc0[jj];
      __syncthreads();
      {
        float s = xv;
        #pragma unroll 8
        for (int k2 = 0; k2 < 32; ++k2)
          s += rbuf[(k2 << 8) + (rbgr << 5) + ((rcol ^ rbgr) << 2) + rbi];
        gbuf[(rcol << 5) + rb] = s;
      }
      __syncthreads();
      if (tid < 64) {
        float gi = gbuf[((0 + cc_) << 5) + b2_];
        float gf = gbuf[((2 + cc_) << 5) + b2_];
        float gg = gbuf[((4 + cc_) << 5) + b2_];
        float go = gbuf[((6 + cc_) << 5) + b2_];
        float i_ = 1.f / (1.f + expf(-gi));
        float f_ = 1.f / (1.f + expf(-gf));
        float o_ = 1.f / (1.f + expf(-go));
        float g_ = tanhf(gg);
        float cn = f_ * creg0 + i_ * g_;
        float hn = o_ * tanhf(cn);
        creg0 = cn;
        __hip_atomic_store(&h0steps[(size_t)u * BH + b2_ * Hd + nn_], hn,
                           __ATOMIC_RELAXED, __HIP_MEMORY_SCOPE_AGENT);
      }
      publish(flag0, u + 1);           // h0(u) visible
      __syncthreads();
    }

    // ---- layer1 reduce + pointwise + publish ----
    if (doL1) {
      #pragma unroll
      for (int jj = 0; jj < 8; ++jj)
        *(float4*)&rbuf[(ks << 8) + (bg << 5) + ((jj ^ bg) << 2)] = *(const float4*)acc1[jj];
      __syncthreads();
      {
        float s = bv;
        #pragma unroll 8
        for (int k2 = 0; k2 < 32; ++k2)
          s += rbuf[(k2 << 8) + (rbgr << 5) + ((rcol ^ rbgr) << 2) + rbi];
        gbuf[(rcol << 5) + rb] = s;
      }
      __syncthreads();
      if (tid < 64) {
        int t = u - 1;
        float gi = gbuf[((0 + cc_) << 5) + b2_];
        float gf = gbuf[((2 + cc_) << 5) + b2_];
        float gg = gbuf[((4 + cc_) << 5) + b2_];
        float go = gbuf[((6 + cc_) << 5) + b2_];
        float i_ = 1.f / (1.f + expf(-gi));
        float f_ = 1.f / (1.f + expf(-gf));
        float o_ = 1.f / (1.f + expf(-go));
        float g_ = tanhf(gg);
        float cn = f_ * creg1 + i_ * g_;
        float hn = o_ * tanhf(cn);
        creg1 = cn;
        __hip_atomic_store(&h1steps[(size_t)t * BH + b2_ * Hd + nn_], hn,
                           __ATOMIC_RELAXED, __HIP_MEMORY_SCOPE_AGENT);
        if (dec_out) dec_out[((size_t)b2_ * SEQ + t) * Hd + nn_] = hn;
      }
      publish(flag1, u);               // h1(u-1) visible
    }
  }

  // final c handoff
  if (tid < 64) {
    c0fin[b2_ * Hd + nn_] = creg0;
    c1fin[b2_ * Hd + nn_] = creg1;
  }
}

// ---------------- host ----------------
extern "C" void kernel_launch(void* const* d_in, const int* in_sizes, int n_in,
                              void* d_out, int out_size, void* d_ws, size_t ws_size,
                              hipStream_t stream) {
  const int*   src  = (const int*)d_in[0];
  const int*   tgt  = (const int*)d_in[1];
  const float* emb  = (const float*)d_in[2];
  const float* Wout = (const float*)d_in[3];
  const float* bout = (const float*)d_in[4];
  const float* eWih0 = (const float*)d_in[5];
  const float* eWhh0 = (const float*)d_in[6];
  const float* ebih0 = (const float*)d_in[7];
  const float* ebhh0 = (const float*)d_in[8];
  const float* eWih1 = (const float*)d_in[9];
  const float* eWhh1 = (const float*)d_in[10];
  const float* ebih1 = (const float*)d_in[11];
  const float* ebhh1 = (const float*)d_in[12];
  const float* dWih0 = (const float*)d_in[13];
  const float* dWhh0 = (const float*)d_in[14];
  const float* dbih0 = (const float*)d_in[15];
  const float* dbhh0 = (const float*)d_in[16];
  const float* dWih1 = (const float*)d_in[17];
  const float* dWhh1 = (const float*)d_in[18];
  const float* dbih1 = (const float*)d_in[19];
  const float* dbhh1 = (const float*)d_in[20];

  float* ws = (float*)d_ws;
  char*  wsb = (char*)d_ws;
  // float offsets
  const size_t OFF_EMB  = 0;          // dead after input gemms
  const size_t OFF_X0   = 1048576;
  const size_t OFF_W0E  = 9437184;
  const size_t OFF_W1AE = 10485760;
  const size_t OFF_W1BE = 11534336;
  const size_t OFF_W0D  = 12582912;
  const size_t OFF_W1AD = 13631488;
  const size_t OFF_W1BD = 14680064;
  const size_t OFF_BS0E = 15728640;
  const size_t OFF_B1E  = 15730688;
  const size_t OFF_BS0D = 15732736;
  const size_t OFF_B1D  = 15734784;
  const size_t OFF_H0   = 15736832;   // 128*BH (per-step h0 slots)
  const size_t OFF_H1   = 17833984;   // 128*BH
  const size_t OFF_C0   = 19931136;   // BH (enc-final c0 -> dec init)
  const size_t OFF_C1   = 19947520;   // BH
  const size_t OFF_Z    = 19963904;   // BH zeros
  const size_t OFF_BAR  = 19980288;   // 4 x 8192 ints (e0,e1,d0,d1)
  const size_t OFF_DOUT = 20013056;   // 2,097,152 f -> byte end 88,440,832
  unsigned short* Ahi = (unsigned short*)(wsb + 88440832);   // 4096*512
  unsigned short* Alo = (unsigned short*)(wsb + 92635136);   // 4096*512
  unsigned short* Bhi = (unsigned short*)(wsb + 0);          // 32000*512 (dead low region)
  unsigned short* Blo = (unsigned short*)(wsb + 32768000);
  const bool use_mfma = ws_size >= 96829440ull;

  int* e0 = (int*)(ws + OFF_BAR);
  int* e1 = e0 + 8192;
  int* d0 = e0 + 16384;
  int* d1 = e0 + 24576;

  // pack weights + bias sums
  pack_w_k<<<256, 256, 0, stream>>>(eWhh0, ws + OFF_W0E);
  pack_w_k<<<256, 256, 0, stream>>>(eWih1, ws + OFF_W1AE);
  pack_w_k<<<256, 256, 0, stream>>>(eWhh1, ws + OFF_W1BE);
  pack_w_k<<<256, 256, 0, stream>>>(dWhh0, ws + OFF_W0D);
  pack_w_k<<<256, 256, 0, stream>>>(dWih1, ws + OFF_W1AD);
  pack_w_k<<<256, 256, 0, stream>>>(dWhh1, ws + OFF_W1BD);
  bias_sum_k<<<8, 256, 0, stream>>>(ebih0, ebhh0, ws + OFF_BS0E);
  bias_sum_k<<<8, 256, 0, stream>>>(ebih1, ebhh1, ws + OFF_B1E);
  bias_sum_k<<<8, 256, 0, stream>>>(dbih0, dbhh0, ws + OFF_BS0D);
  bias_sum_k<<<8, 256, 0, stream>>>(dbih1, dbhh1, ws + OFF_B1D);

  // zero zbuf + all flag arrays every call (graph replay safe)
  hipMemsetAsync(ws + OFF_Z, 0, (size_t)(BH + 32768) * 4, stream);

  // encoder
  embed_k<<<1024, 256, 0, stream>>>(src, emb, ws + OFF_EMB);
  gemm_nt_k<<<dim3(32, 64), 256, 0, stream>>>(ws + OFF_EMB, eWih0, ws + OFF_BS0E,
                                              ws + OFF_X0, 256, 2048);
  lstm_seq_k<<<256, 256, 0, stream>>>(ws + OFF_W0E, ws + OFF_W1AE, ws + OFF_W1BE,
                                      ws + OFF_X0, ws + OFF_B1E,
                                      ws + OFF_H0, ws + OFF_H1,
                                      ws + OFF_Z, ws + OFF_Z,      // h inits (zeros)
                                      ws + OFF_Z, ws + OFF_Z,      // c inits (zeros)
                                      ws + OFF_C0, ws + OFF_C1,    // c finals
                                      nullptr, e0, e1);

  // decoder (inits = encoder finals)
  embed_k<<<1024, 256, 0, stream>>>(tgt, emb, ws + OFF_EMB);
  gemm_nt_k<<<dim3(32, 64), 256, 0, stream>>>(ws + OFF_EMB, dWih0, ws + OFF_BS0D,
                                              ws + OFF_X0, 256, 2048);
  lstm_seq_k<<<256, 256, 0, stream>>>(ws + OFF_W0D, ws + OFF_W1AD, ws + OFF_W1BD,
                                      ws + OFF_X0, ws + OFF_B1D,
                                      ws + OFF_H0, ws + OFF_H1,
                                      ws + OFF_H0 + (size_t)127 * BH,
                                      ws + OFF_H1 + (size_t)127 * BH,
                                      ws + OFF_C0, ws + OFF_C1,
                                      ws + OFF_C0, ws + OFF_C1,
                                      ws + OFF_DOUT, d0, d1);

  // vocab projection
  if (use_mfma) {
    split_k<<<2048, 256, 0, stream>>>(ws + OFF_DOUT, Ahi, Alo);
    split_k<<<16000, 256, 0, stream>>>(Wout, Bhi, Blo);   // overlays dead low region
    gemm_bf16_split_k<<<dim3(32, 250), 256, 0, stream>>>(Ahi, Alo, Bhi, Blo,
                                                         bout, (float*)d_out);
  } else {
    gemm_nt_k<<<dim3(500, 64), 256, 0, stream>>>(ws + OFF_DOUT, Wout, bout,
                                                 (float*)d_out, 512, 32000);
  }
}